// Round 4
// baseline (350.197 us; speedup 1.0000x reference)
//
#include <hip/hip_runtime.h>
#include <hip/hip_bf16.h>
#include <math.h>

#define DEV static __device__ __forceinline__

typedef __attribute__((ext_vector_type(4))) float f32x4;
typedef __attribute__((ext_vector_type(8))) __bf16 bf16x8;
typedef __attribute__((ext_vector_type(8))) short s16x8;
typedef __attribute__((ext_vector_type(2))) _Float16 h16x2;

DEV float b2f(short v){ unsigned u = ((unsigned)(unsigned short)v) << 16; float f; __builtin_memcpy(&f, &u, 4); return f; }
DEV short f2b(float f){ unsigned u; __builtin_memcpy(&u, &f, 4); unsigned r = (u + 0x7fffu + ((u >> 16) & 1u)) >> 16; return (short)r; }
DEV short f2h(float f){ _Float16 h = (_Float16)f; short s; __builtin_memcpy(&s, &h, 2); return s; }
DEV float h2f(short s){ _Float16 h; __builtin_memcpy(&h, &s, 2); return (float)h; }
DEV h16x2 u2h2(unsigned u){ h16x2 h; __builtin_memcpy(&h, &u, 4); return h; }
DEV float gelu_f(float v){ return 0.5f * v * (1.0f + erff(v * 0.70710678118654752f)); }

DEV void gload16(const void* g, void* l) {
  __builtin_amdgcn_global_load_lds((const __attribute__((address_space(1))) unsigned int*)g,
                                   (__attribute__((address_space(3))) unsigned int*)l, 16, 0, 0);
}

// XCD-bijective swizzle over a 2D grid (requires nx*ny % 8 == 0); keeps n-fastest order per XCD
DEV void xy_swz(int& bx, int& by, int nx, int ny) {
  int lin = by * nx + bx;
  int q = (nx * ny) >> 3;
  int l2 = (lin & 7) * q + (lin >> 3);
  bx = l2 % nx; by = l2 / nx;
}

// ---------------- fused cast fp32 -> bf16 for x and hist ----------------
__global__ __launch_bounds__(256) void k_cast_all(const float* __restrict__ x, const float* __restrict__ hist,
                                                  short* __restrict__ xb, short* __restrict__ histb){
  int bid = blockIdx.x;
  const float* in; short* out; int i;
  if (bid < 2048) { in = x; out = xb; i = (bid * 256 + threadIdx.x) * 8; }
  else            { in = hist; out = histb; i = ((bid - 2048) * 256 + threadIdx.x) * 8; }
  f32x4 a = *(const f32x4*)&in[i];
  f32x4 b = *(const f32x4*)&in[i + 4];
  s16x8 o;
  o[0]=f2b(a[0]); o[1]=f2b(a[1]); o[2]=f2b(a[2]); o[3]=f2b(a[3]);
  o[4]=f2b(b[0]); o[5]=f2b(b[1]); o[6]=f2b(b[2]); o[7]=f2b(b[3]);
  *(s16x8*)&out[i] = o;
}

// ---------------- all weight transpose-casts in one launch ----------------
DEV void tcast_tile(const float* __restrict__ W, short* __restrict__ Wt, int K, int N, int tx, int ty){
  __shared__ float tile[32][33];
  int nb = tx * 32, kb = ty * 32;
  int tid = threadIdx.x;
  int c = tid & 31, r0 = tid >> 5;
  #pragma unroll
  for (int r = r0; r < 32; r += 8) tile[r][c] = W[(size_t)(kb + r) * N + nb + c];
  __syncthreads();
  #pragma unroll
  for (int r = r0; r < 32; r += 8) Wt[(size_t)(nb + r) * K + kb + c] = f2b(tile[c][r]);
}
__global__ __launch_bounds__(256) void k_tcast_all(const float* __restrict__ Wq, const float* __restrict__ Wk,
                                                   const float* __restrict__ Wv, const float* __restrict__ projW,
                                                   const float* __restrict__ histW, const float* __restrict__ ctxW1,
                                                   short* __restrict__ wqkvt, short* __restrict__ wptb,
                                                   short* __restrict__ whtb, short* __restrict__ wc1tb){
  int bid = blockIdx.x;
  const float* W; short* Wt; int K, N, tx, ty;
  if (bid < 4096) {
    int seg = bid >> 10, t = bid & 1023;
    tx = t & 31; ty = t >> 5; K = 1024; N = 1024;
    if      (seg == 0) { W = Wq;    Wt = wqkvt; }
    else if (seg == 1) { W = Wk;    Wt = wqkvt + 1024*1024; }
    else if (seg == 2) { W = Wv;    Wt = wqkvt + 2*1024*1024; }
    else               { W = projW; Wt = wptb; }
  } else if (bid < 6144) {
    int t = bid - 4096; tx = t & 63; ty = t >> 6; K = 1024; N = 2048; W = histW; Wt = whtb;
  } else {
    int t = bid - 6144; tx = t & 15; ty = t >> 4; K = 2048; N = 512; W = ctxW1; Wt = wc1tb;
  }
  tcast_tile(W, Wt, K, N, tx, ty);
}

// ---------------- GEMM core: per-wave acc = A[m0:m0+128, :K] * Bt[n0:n0+128, :K]^T ----------------
DEV void gemm_core(const short* __restrict__ A, const short* __restrict__ Bt,
                   int K, int lda, int ldb, int m0, int n0,
                   short* lA, short* lB, f32x4 acc[4][4])
{
  const int tid = threadIdx.x;
  const int lane = tid & 63;
  const int w = tid >> 6;
  const int wr = (w >> 1) * 64, wc = (w & 1) * 64;
  const int lr = lane & 15, lk = (lane >> 4) * 8;
  for (int kt = 0; kt < K; kt += 64) {
    __syncthreads();
    #pragma unroll
    for (int i = 0; i < 4; ++i) {
      int off = i * 2048 + tid * 8;
      int r = off >> 6, c = off & 63;
      gload16(&A[(size_t)(m0 + r) * lda + kt + c], &lA[off]);
      gload16(&Bt[(size_t)(n0 + r) * ldb + kt + c], &lB[off]);
    }
    __syncthreads();
    #pragma unroll
    for (int kk = 0; kk < 64; kk += 32) {
      bf16x8 af[4], bfr[4];
      #pragma unroll
      for (int mi = 0; mi < 4; ++mi) af[mi] = *(bf16x8*)&lA[(wr + mi*16 + lr)*64 + kk + lk];
      #pragma unroll
      for (int ni = 0; ni < 4; ++ni) bfr[ni] = *(bf16x8*)&lB[(wc + ni*16 + lr)*64 + kk + lk];
      #pragma unroll
      for (int mi = 0; mi < 4; ++mi)
        #pragma unroll
        for (int ni = 0; ni < 4; ++ni)
          acc[mi][ni] = __builtin_amdgcn_mfma_f32_16x16x32_bf16(af[mi], bfr[ni], acc[mi][ni], 0, 0, 0);
    }
  }
}

// ---------------- GEMM with fp32 output (+bias, optional gelu) ----------------
__global__ __launch_bounds__(256) void k_gemm_f32out(const short* __restrict__ A, const short* __restrict__ Bt,
                                                     float* __restrict__ Cout, const float* __restrict__ bias,
                                                     int N, int K, int doGelu)
{
  __shared__ __align__(16) short lds[2 * 128 * 64];
  f32x4 acc[4][4] = {};
  int bx = blockIdx.x, by = blockIdx.y;
  xy_swz(bx, by, gridDim.x, gridDim.y);
  int m0 = by * 128, n0 = bx * 128;
  gemm_core(A, Bt, K, K, K, m0, n0, lds, lds + 128*64, acc);
  int lane = threadIdx.x & 63, w = threadIdx.x >> 6;
  int wr = (w>>1)*64, wc = (w&1)*64, lr4 = (lane>>4)*4, lc = lane & 15;
  #pragma unroll
  for (int mi = 0; mi < 4; ++mi)
    #pragma unroll
    for (int ni = 0; ni < 4; ++ni)
      #pragma unroll
      for (int r = 0; r < 4; ++r) {
        int row = m0 + wr + mi*16 + lr4 + r;
        int col = n0 + wc + ni*16 + lc;
        float v = acc[mi][ni][r] + bias[col];
        if (doGelu) v = gelu_f(v);
        Cout[(size_t)row * N + col] = v;
      }
}

// ---------------- fused QKV GEMM: x[4096,1024] @ Wqkv^T, heads epilogue (LDS-repacked stores) ----------------
__global__ __launch_bounds__(256) void k_gemm_qkv(const short* __restrict__ xb, const short* __restrict__ wqkvt,
                                                  short* __restrict__ q, short* __restrict__ kk, short* __restrict__ vt)
{
  __shared__ __align__(16) short lds[128 * 136];
  f32x4 acc[4][4] = {};
  int bx = blockIdx.x, by = blockIdx.y;
  xy_swz(bx, by, gridDim.x, gridDim.y);
  int m0 = by * 128, n0 = bx * 128;
  gemm_core(xb, wqkvt, 1024, 1024, 1024, m0, n0, lds, lds + 128*64, acc);
  int tid = threadIdx.x, lane = tid & 63, w = tid >> 6;
  int wr = (w>>1)*64, wc = (w&1)*64, lr4 = (lane>>4)*4, lc = lane & 15;
  int bb = m0 >> 10, tm0 = m0 & 1023;
  int s = n0 >> 10, dn0 = n0 & 1023;
  __syncthreads();
  if (s < 2) {
    short* dst = (s == 0) ? q : kk;
    #pragma unroll
    for (int mi = 0; mi < 4; ++mi)
      #pragma unroll
      for (int ni = 0; ni < 4; ++ni)
        #pragma unroll
        for (int r = 0; r < 4; ++r)
          lds[(wr + mi*16 + lr4 + r) * 136 + wc + ni*16 + lc] = f2b(acc[mi][ni][r]);
    __syncthreads();
    #pragma unroll
    for (int it = 0; it < 8; ++it) {
      int idx = it * 256 + tid;
      int row = idx >> 4, ch = (idx & 15) * 8;
      int dfull = dn0 + ch;
      *(s16x8*)&dst[(((size_t)(bb*16 + (dfull >> 6)) * 1024 + tm0 + row) << 6) + (dfull & 63)]
          = *(s16x8*)&lds[row * 136 + ch];
    }
  } else {
    #pragma unroll
    for (int mi = 0; mi < 4; ++mi)
      #pragma unroll
      for (int ni = 0; ni < 4; ++ni)
        #pragma unroll
        for (int r = 0; r < 4; ++r)
          lds[(wc + ni*16 + lc) * 136 + wr + mi*16 + lr4 + r] = f2b(acc[mi][ni][r]);
    __syncthreads();
    #pragma unroll
    for (int it = 0; it < 8; ++it) {
      int idx = it * 256 + tid;
      int nl = idx >> 4, mc = (idx & 15) * 8;
      int dfull = dn0 + nl;
      *(s16x8*)&vt[(((size_t)(bb*16 + (dfull >> 6)) * 64 + (dfull & 63)) << 10) + tm0 + mc]
          = *(s16x8*)&lds[nl * 136 + mc];
    }
  }
}

// ---------------- scores: S = q@k^T * 0.125, causal-zeroed, FP16, vectorized stores ----------------
__global__ __launch_bounds__(256) void k_gemm_scores(const short* __restrict__ q, const short* __restrict__ kk,
                                                     short* __restrict__ S)
{
  int nt = blockIdx.x, mt = blockIdx.y, bh = blockIdx.z;
  if (nt > mt) return;
  __shared__ __align__(16) short lds[128 * 136];
  f32x4 acc[4][4] = {};
  const short* A  = q  + ((size_t)bh << 16);
  const short* Bt = kk + ((size_t)bh << 16);
  int m0 = mt * 128, n0 = nt * 128;
  gemm_core(A, Bt, 64, 64, 64, m0, n0, lds, lds + 128*64, acc);
  short* Sp = S + ((size_t)bh << 20);
  int tid = threadIdx.x, lane = tid & 63, w = tid >> 6;
  int wr = (w>>1)*64, wc = (w&1)*64, lr4 = (lane>>4)*4, lc = lane & 15;
  __syncthreads();
  #pragma unroll
  for (int mi = 0; mi < 4; ++mi)
    #pragma unroll
    for (int ni = 0; ni < 4; ++ni)
      #pragma unroll
      for (int r = 0; r < 4; ++r) {
        int ml = wr + mi*16 + lr4 + r;
        int nl = wc + ni*16 + lc;
        float v = acc[mi][ni][r] * 0.125f;
        if (n0 + nl > m0 + ml) v = 0.0f;
        lds[ml * 136 + nl] = f2h(v);
      }
  __syncthreads();
  #pragma unroll
  for (int it = 0; it < 8; ++it) {
    int idx = it * 256 + tid;
    int row = idx >> 4, ch = (idx & 15) * 8;
    *(s16x8*)&Sp[((size_t)(m0 + row) << 10) + n0 + ch] = *(s16x8*)&lds[row * 136 + ch];
  }
  // cross-tile zeros: every row r needs S[r][r+1..r+2] == 0; only rows 126/127 of a
  // diagonal tile spill into the next column tile.
  if (nt == mt && mt < 7 && tid == 0) {
    Sp[((size_t)(m0 + 126) << 10) + m0 + 128] = 0;
    Sp[((size_t)(m0 + 127) << 10) + m0 + 128] = 0;
    Sp[((size_t)(m0 + 127) << 10) + m0 + 129] = 0;
  }
}

// ---------------- fused conv3x3 + mask + softmax + PV (S in f16, no max pass) ----------------
constexpr int CPSTR = 1040;     // shorts; 2080B row stride

DEV void conv_chunk(const short* sS, int rbase, int c,
                    const h16x2 wp01[3], const h16x2 wp2z[3], float o[8]) {
  #pragma unroll
  for (int t = 0; t < 8; ++t) o[t] = 0.0f;
  #pragma unroll
  for (int dr = 0; dr < 3; ++dr) {
    int base = (rbase + dr) * CPSTR + 8 + c;
    const unsigned* W = (const unsigned*)&sS[base];
    unsigned U0 = W[0], U1 = W[1], U2 = W[2], U3 = W[3];
    unsigned hm1 = (unsigned short)sS[base - 1];
    unsigned hp8 = (unsigned short)sS[base + 8];
    unsigned P0 = hm1 | (U0 << 16);
    unsigned P2 = (U0 >> 16) | (U1 << 16);
    unsigned P4 = (U1 >> 16) | (U2 << 16);
    unsigned P6 = (U2 >> 16) | (U3 << 16);
    unsigned P8 = (U3 >> 16) | (hp8 << 16);
    unsigned P9 = hp8;
    unsigned pr[10] = {P0, U0, P2, U1, P4, U2, P6, U3, P8, P9};
    h16x2 a = wp01[dr], bz = wp2z[dr];
    #pragma unroll
    for (int t = 0; t < 8; ++t) {
      o[t] = __builtin_amdgcn_fdot2(a,  u2h2(pr[t]),     o[t], false);
      o[t] = __builtin_amdgcn_fdot2(bz, u2h2(pr[t + 2]), o[t], false);
    }
  }
}

__global__ __launch_bounds__(256, 4) void k_conv_softmax_pv(const short* __restrict__ S, const short* __restrict__ vt,
                                                            const float* __restrict__ kern, short* __restrict__ O)
{
  __shared__ __align__(16) short sS[18 * CPSTR];
  __shared__ float sInv[16];
  int bh = blockIdx.y, b = bh >> 4, h = bh & 15;
  int q0 = blockIdx.x * 16;
  int tid = threadIdx.x;
  int g = tid >> 4, i = tid & 15;
  int qrow = q0 + g;
  const short* Sp = S + ((size_t)bh << 20);
  int SCOLS = (((q0 + 16) >> 7) + 1) * 128; if (SCOLS > 1024) SCOLS = 1024;
  int nj = SCOLS >> 7;

  s16x8 zz = {};
  if (tid < 18) {
    *(s16x8*)&sS[tid * CPSTR] = zz;                 // left pad
    *(s16x8*)&sS[tid * CPSTR + 8 + SCOLS] = zz;     // right pad
  }
  // ---- stage S rows q0-1 .. q0+16 via global_load_lds (wave-uniform row, lane*16B) ----
  {
    int r_off = tid >> 7;            // wave-pair row offset
    int col = (tid & 127) * 8;
    #pragma unroll
    for (int rr = 0; rr < 18; rr += 2) {
      int r = rr + r_off;
      int qq = q0 - 1 + r;
      if (col < SCOLS) {
        if (qq >= 0 && qq < 1024)
          gload16(&Sp[((size_t)qq << 10) + col], &sS[r * CPSTR + 8 + col]);
        else
          *(s16x8*)&sS[r * CPSTR + 8 + col] = zz;
      }
    }
  }
  h16x2 wp01[3], wp2z[3];
  #pragma unroll
  for (int a = 0; a < 3; ++a) {
    wp01[a][0] = (_Float16)kern[bh * 9 + a * 3 + 0];
    wp01[a][1] = (_Float16)kern[bh * 9 + a * 3 + 1];
    wp2z[a][0] = (_Float16)kern[bh * 9 + a * 3 + 2];
    wp2z[a][1] = (_Float16)0.0f;
  }
  __syncthreads();

  // ---- single pass: conv, exp (no max shift needed: |o| <~ 10), pack P, sum ----
  float sum = 0.0f;
  s16x8 ps[8];
  #pragma unroll 8
  for (int j = 0; j < 8; ++j) if (j < nj) {
    int c = i * 8 + j * 128;
    float o[8]; conv_chunk(sS, g, c, wp01, wp2z, o);
    s16x8 po;
    #pragma unroll
    for (int t = 0; t < 8; ++t) {
      float e = (c + t <= qrow) ? __expf(o[t]) : 0.0f;
      sum += e;
      po[t] = f2b(e);
    }
    ps[j] = po;
  }
  #pragma unroll
  for (int off = 1; off < 16; off <<= 1) sum += __shfl_xor(sum, off);
  __syncthreads();                    // all conv reads complete before overwrite

  #pragma unroll 8
  for (int j = 0; j < 8; ++j) if (j < nj)
    *(s16x8*)&sS[g * CPSTR + i * 8 + j * 128] = ps[j];
  if (i == 0) sInv[g] = 1.0f / sum;
  __syncthreads();

  // ---- PV: O_blk[16,64] = P[16,klim] @ V ----
  int lane = tid & 63, w = tid >> 6;
  int n0w = w * 16;
  int lr = lane & 15, lk = (lane >> 4) * 8;
  f32x4 acc = {0, 0, 0, 0};
  int klim = ((q0 + 16 + 31) >> 5) << 5;
  for (int k0 = 0; k0 < klim; k0 += 32) {
    bf16x8 a  = *(bf16x8*)&sS[lr * CPSTR + k0 + lk];
    bf16x8 bv = *(const bf16x8*)&vt[(((size_t)bh * 64 + n0w + lr) << 10) + k0 + lk];
    acc = __builtin_amdgcn_mfma_f32_16x16x32_bf16(a, bv, acc, 0, 0, 0);
  }
  int r0 = (lane >> 4) * 4;
  #pragma unroll
  for (int r = 0; r < 4; ++r) {
    int rw = r0 + r;
    float ov = acc[r] * sInv[rw];
    O[((size_t)(b * 1024 + q0 + rw) << 10) + h * 64 + n0w + lr] = f2b(ov);
  }
}

// ---------------- LN + gelu, fp32[*,2048] -> bf16, vectorized ----------------
__global__ __launch_bounds__(256) void k_ln_gelu2048(const float* __restrict__ x, const float* __restrict__ g,
                                                     const float* __restrict__ be, short* __restrict__ out)
{
  __shared__ float red[8];
  int row = blockIdx.x, tid = threadIdx.x;
  const float* xr = x + (size_t)row * 2048;
  int c0 = tid * 8;
  f32x4 a = *(const f32x4*)&xr[c0];
  f32x4 bb = *(const f32x4*)&xr[c0 + 4];
  float s = 0, s2 = 0;
  #pragma unroll
  for (int t = 0; t < 4; ++t) { s += a[t] + bb[t]; s2 += a[t]*a[t] + bb[t]*bb[t]; }
  #pragma unroll
  for (int off = 32; off; off >>= 1) { s += __shfl_xor(s, off); s2 += __shfl_xor(s2, off); }
  if ((tid & 63) == 0) { red[tid >> 6] = s; red[4 + (tid >> 6)] = s2; }
  __syncthreads();
  s  = red[0] + red[1] + red[2] + red[3];
  s2 = red[4] + red[5] + red[6] + red[7];
  float mean = s * (1.0f / 2048.0f);
  float var  = s2 * (1.0f / 2048.0f) - mean * mean;
  float inv  = rsqrtf(var + 1e-5f);
  f32x4 g0 = *(const f32x4*)&g[c0],  g1 = *(const f32x4*)&g[c0 + 4];
  f32x4 e0 = *(const f32x4*)&be[c0], e1 = *(const f32x4*)&be[c0 + 4];
  s16x8 o;
  #pragma unroll
  for (int t = 0; t < 4; ++t) {
    o[t]     = f2b(gelu_f((a[t]  - mean) * inv * g0[t] + e0[t]));
    o[t + 4] = f2b(gelu_f((bb[t] - mean) * inv * g1[t] + e1[t]));
  }
  *(s16x8*)&out[(size_t)row * 2048 + c0] = o;
}

// ---------------- ctx tail: logits + softmax + weighted pool, one block per batch ----------------
__global__ __launch_bounds__(1024) void k_ctx_tail(const float* __restrict__ t, const float* __restrict__ w2,
                                                   const float* __restrict__ b2, const short* __restrict__ ehb,
                                                   float* __restrict__ cc)
{
  __shared__ float sl[256];
  __shared__ float r2[8];
  int b = blockIdx.x, tid = threadIdx.x;
  // logits: 4 threads per row
  {
    int row = tid >> 2, part = tid & 3;
    const float* tr = t + ((size_t)(b * 256 + row)) * 512 + part * 128;
    const float* wr = w2 + part * 128;
    float s = 0;
    #pragma unroll 8
    for (int c4 = 0; c4 < 128; c4 += 4) {
      f32x4 tv = *(const f32x4*)&tr[c4];
      f32x4 wv = *(const f32x4*)&wr[c4];
      s += tv[0]*wv[0] + tv[1]*wv[1] + tv[2]*wv[2] + tv[3]*wv[3];
    }
    s += __shfl_xor(s, 1);
    s += __shfl_xor(s, 2);
    if (part == 0) sl[row] = s + b2[0];
  }
  __syncthreads();
  if (tid < 256) {
    float m = sl[tid];
    #pragma unroll
    for (int off = 32; off; off >>= 1) m = fmaxf(m, __shfl_xor(m, off));
    if ((tid & 63) == 0) r2[tid >> 6] = m;
  }
  __syncthreads();
  float M = fmaxf(fmaxf(r2[0], r2[1]), fmaxf(r2[2], r2[3]));
  if (tid < 256) {
    float e = __expf(sl[tid] - M);
    float s = e;
    #pragma unroll
    for (int off = 32; off; off >>= 1) s += __shfl_xor(s, off);
    if ((tid & 63) == 0) r2[4 + (tid >> 6)] = s;
    sl[tid] = e;
  }
  __syncthreads();
  float invT = 1.0f / (r2[4] + r2[5] + r2[6] + r2[7]);
  float a0 = 0, a1 = 0;
  for (int tt = 0; tt < 256; ++tt) {
    float wv = sl[tt];
    const short* er = &ehb[((size_t)(b * 256 + tt)) << 11];
    a0 += wv * b2f(er[tid]);
    a1 += wv * b2f(er[1024 + tid]);
  }
  cc[(b << 11) + tid] = a0 * invT;
  cc[(b << 11) + 1024 + tid] = a1 * invT;
}

// ---------------- kg1 split-K partials: part[kc*4+b][1024] ----------------
__global__ __launch_bounds__(256) void k_kg1p(const float* __restrict__ cc, const float* __restrict__ W1,
                                              float* __restrict__ part)
{
  int d = blockIdx.x * 256 + threadIdx.x;
  int kc = blockIdx.y;
  float s0 = 0, s1 = 0, s2 = 0, s3 = 0;
  for (int k = kc * 256; k < kc * 256 + 256; ++k) {
    float w = W1[(size_t)k * 1024 + d];
    s0 += cc[k] * w; s1 += cc[2048 + k] * w; s2 += cc[4096 + k] * w; s3 += cc[6144 + k] * w;
  }
  part[(size_t)(kc * 4 + 0) * 1024 + d] = s0;
  part[(size_t)(kc * 4 + 1) * 1024 + d] = s1;
  part[(size_t)(kc * 4 + 2) * 1024 + d] = s2;
  part[(size_t)(kc * 4 + 3) * 1024 + d] = s3;
}

// ---------------- kg mid: reduce partials + bias, LN, gelu -> kgh bf16 (one block per batch) ----------------
__global__ __launch_bounds__(256) void k_kg_mid(const float* __restrict__ part, const float* __restrict__ b1,
                                                const float* __restrict__ g, const float* __restrict__ be,
                                                short* __restrict__ kgh)
{
  __shared__ float red[8];
  int b = blockIdx.x, tid = threadIdx.x;
  float v[4]; float s = 0, s2 = 0;
  #pragma unroll
  for (int qi = 0; qi < 4; ++qi) {
    int d = tid + qi * 256;
    float acc = b1[d];
    #pragma unroll
    for (int kc = 0; kc < 8; ++kc) acc += part[(size_t)(kc * 4 + b) * 1024 + d];
    v[qi] = acc; s += acc; s2 += acc * acc;
  }
  #pragma unroll
  for (int off = 32; off; off >>= 1) { s += __shfl_xor(s, off); s2 += __shfl_xor(s2, off); }
  if ((tid & 63) == 0) { red[tid >> 6] = s; red[4 + (tid >> 6)] = s2; }
  __syncthreads();
  s  = red[0] + red[1] + red[2] + red[3];
  s2 = red[4] + red[5] + red[6] + red[7];
  float mean = s * (1.0f / 1024.0f);
  float var  = s2 * (1.0f / 1024.0f) - mean * mean;
  float inv  = rsqrtf(var + 1e-5f);
  #pragma unroll
  for (int qi = 0; qi < 4; ++qi) {
    int d = tid + qi * 256;
    kgh[b * 1024 + d] = f2b(gelu_f((v[qi] - mean) * inv * g[d] + be[d]));
  }
}

// ---------------- kp + softmax9: one wave per (h,b) ----------------
__global__ __launch_bounds__(64) void k_kp2(const short* __restrict__ kgh, const float* __restrict__ W2,
                                            const float* __restrict__ b2, float* __restrict__ kern)
{
  int h = blockIdx.x, b = blockIdx.y, lane = threadIdx.x;
  float kg[16];
  #pragma unroll
  for (int m = 0; m < 16; ++m) kg[m] = b2f(kgh[b * 1024 + lane + m * 64]);
  float dj[9];
  #pragma unroll
  for (int j = 0; j < 9; ++j) {
    float s = 0;
    #pragma unroll
    for (int m = 0; m < 16; ++m) s += kg[m] * W2[(size_t)(lane + m * 64) * 144 + h * 9 + j];
    #pragma unroll
    for (int off = 32; off; off >>= 1) s += __shfl_xor(s, off);
    dj[j] = s + b2[h * 9 + j];
  }
  if (lane == 0) {
    float m = dj[0];
    #pragma unroll
    for (int j = 1; j < 9; ++j) m = fmaxf(m, dj[j]);
    float e[9], s = 0;
    #pragma unroll
    for (int j = 0; j < 9; ++j) { e[j] = __expf(dj[j] - m); s += e[j]; }
    float inv = 1.0f / s;
    #pragma unroll
    for (int j = 0; j < 9; ++j) kern[(b * 16 + h) * 9 + j] = e[j] * inv;
  }
}

__global__ void k_fail(float* out){ out[threadIdx.x] = 1.0e9f; }

extern "C" void kernel_launch(void* const* d_in, const int* in_sizes, int n_in,
                              void* d_out, int out_size, void* d_ws, size_t ws_size,
                              hipStream_t stream) {
  (void)in_sizes; (void)n_in; (void)out_size;
  const float* x       = (const float*)d_in[0];
  const float* hist    = (const float*)d_in[1];
  const float* Wq      = (const float*)d_in[2];
  const float* Wk      = (const float*)d_in[3];
  const float* Wv      = (const float*)d_in[4];
  const float* hist_W  = (const float*)d_in[5];
  const float* hist_b  = (const float*)d_in[6];
  const float* hln_g   = (const float*)d_in[7];
  const float* hln_b   = (const float*)d_in[8];
  const float* ctx_W1  = (const float*)d_in[9];
  const float* ctx_b1  = (const float*)d_in[10];
  const float* ctx_W2  = (const float*)d_in[11];
  const float* ctx_b2  = (const float*)d_in[12];
  const float* kg_W1   = (const float*)d_in[13];
  const float* kg_b1   = (const float*)d_in[14];
  const float* kln_g   = (const float*)d_in[15];
  const float* kln_b   = (const float*)d_in[16];
  const float* kg_W2   = (const float*)d_in[17];
  const float* kg_b2   = (const float*)d_in[18];
  const float* proj_W  = (const float*)d_in[19];
  const float* proj_b  = (const float*)d_in[20];
  float* outp = (float*)d_out;

  char* wsb = (char*)d_ws;
  size_t off = 0;
  auto nxt = [&](size_t bytes) { void* p = wsb + off; off += (bytes + 255) & ~(size_t)255; return p; };

  short* xb     = (short*)nxt((size_t)4096*1024*2);
  short* wqkvt  = (short*)nxt((size_t)3*1024*1024*2);
  short* qb     = (short*)nxt((size_t)64*1024*64*2);
  short* kb     = (short*)nxt((size_t)64*1024*64*2);
  short* vtb    = (short*)nxt((size_t)64*64*1024*2);
  short* Sb     = (short*)nxt((size_t)64*1024*1024*2);
  short* Ob     = (short*)nxt((size_t)4096*1024*2);
  short* histb  = (short*)nxt((size_t)1024*1024*2);
  short* whtb   = (short*)nxt((size_t)2048*1024*2);
  float* ehpre  = (float*)nxt((size_t)1024*2048*4);
  short* ehb    = (short*)nxt((size_t)1024*2048*2);
  short* wc1tb  = (short*)nxt((size_t)512*2048*2);
  float* tbuf   = (float*)nxt((size_t)1024*512*4);
  float* ccb    = (float*)nxt((size_t)4*2048*4);
  float* kgpart = (float*)nxt((size_t)32*1024*4);
  short* kghb   = (short*)nxt((size_t)4*1024*2);
  float* kernb  = (float*)nxt((size_t)64*9*4);
  short* wptb   = (short*)nxt((size_t)1024*1024*2);

  if (ws_size < off) { k_fail<<<1, 64, 0, stream>>>(outp); return; }

  // casts + weight transposes (fused launches)
  k_cast_all<<<2560, 256, 0, stream>>>(x, hist, xb, histb);
  k_tcast_all<<<7168, 256, 0, stream>>>(Wq, Wk, Wv, proj_W, hist_W, ctx_W1, wqkvt, wptb, whtb, wc1tb);

  // context path
  k_gemm_f32out<<<dim3(16, 8), 256, 0, stream>>>(histb, whtb, ehpre, hist_b, 2048, 1024, 0);
  k_ln_gelu2048<<<1024, 256, 0, stream>>>(ehpre, hln_g, hln_b, ehb);
  k_gemm_f32out<<<dim3(4, 8), 256, 0, stream>>>(ehb, wc1tb, tbuf, ctx_b1, 512, 2048, 1);
  k_ctx_tail<<<4, 1024, 0, stream>>>(tbuf, ctx_W2, ctx_b2, ehb, ccb);
  k_kg1p<<<dim3(4, 8), 256, 0, stream>>>(ccb, kg_W1, kgpart);
  k_kg_mid<<<4, 256, 0, stream>>>(kgpart, kg_b1, kln_g, kln_b, kghb);
  k_kp2<<<dim3(16, 4), 64, 0, stream>>>(kghb, kg_W2, kg_b2, kernb);

  // attention path
  k_gemm_qkv<<<dim3(24, 32), 256, 0, stream>>>(xb, wqkvt, qb, kb, vtb);
  k_gemm_scores<<<dim3(8, 8, 64), 256, 0, stream>>>(qb, kb, Sb);
  k_conv_softmax_pv<<<dim3(64, 64), 256, 0, stream>>>(Sb, vtb, kernb, Ob);
  k_gemm_f32out<<<dim3(8, 32), 256, 0, stream>>>(Ob, wptb, outp, proj_b, 1024, 1024, 0);
}

// Round 6
// 310.525 us; speedup vs baseline: 1.1278x; 1.1278x over previous
//
#include <hip/hip_runtime.h>
#include <hip/hip_bf16.h>
#include <math.h>

#define DEV static __device__ __forceinline__

typedef __attribute__((ext_vector_type(4))) float f32x4;
typedef __attribute__((ext_vector_type(8))) __bf16 bf16x8;
typedef __attribute__((ext_vector_type(8))) short s16x8;
typedef __attribute__((ext_vector_type(2))) _Float16 h16x2;

DEV float b2f(short v){ unsigned u = ((unsigned)(unsigned short)v) << 16; float f; __builtin_memcpy(&f, &u, 4); return f; }
DEV short f2b(float f){ unsigned u; __builtin_memcpy(&u, &f, 4); unsigned r = (u + 0x7fffu + ((u >> 16) & 1u)) >> 16; return (short)r; }
DEV short f2h(float f){ _Float16 h = (_Float16)f; short s; __builtin_memcpy(&s, &h, 2); return s; }
DEV h16x2 u2h2(unsigned u){ h16x2 h; __builtin_memcpy(&h, &u, 4); return h; }
DEV float gelu_f(float v){ return 0.5f * v * (1.0f + erff(v * 0.70710678118654752f)); }

DEV void gload16(const void* g, void* l) {
  __builtin_amdgcn_global_load_lds((const __attribute__((address_space(1))) unsigned int*)g,
                                   (__attribute__((address_space(3))) unsigned int*)l, 16, 0, 0);
}

// XCD-bijective swizzle over a 2D grid (requires nx*ny % 8 == 0)
DEV void xy_swz(int& bx, int& by, int nx, int ny) {
  int lin = by * nx + bx;
  int q = (nx * ny) >> 3;
  int l2 = (lin & 7) * q + (lin >> 3);
  bx = l2 % nx; by = l2 / nx;
}

// ---------------- fused cast fp32 -> bf16 for x and hist ----------------
__global__ __launch_bounds__(256) void k_cast_all(const float* __restrict__ x, const float* __restrict__ hist,
                                                  short* __restrict__ xb, short* __restrict__ histb){
  int bid = blockIdx.x;
  const float* in; short* out; int i;
  if (bid < 2048) { in = x; out = xb; i = (bid * 256 + threadIdx.x) * 8; }
  else            { in = hist; out = histb; i = ((bid - 2048) * 256 + threadIdx.x) * 8; }
  f32x4 a = *(const f32x4*)&in[i];
  f32x4 b = *(const f32x4*)&in[i + 4];
  s16x8 o;
  o[0]=f2b(a[0]); o[1]=f2b(a[1]); o[2]=f2b(a[2]); o[3]=f2b(a[3]);
  o[4]=f2b(b[0]); o[5]=f2b(b[1]); o[6]=f2b(b[2]); o[7]=f2b(b[3]);
  *(s16x8*)&out[i] = o;
}

// ---------------- zero the halo pad rows (0 and 1025) of padded q/k ----------------
__global__ __launch_bounds__(256) void k_zero_qk_pads(short* __restrict__ q, short* __restrict__ kk){
  int idx = blockIdx.x * 256 + threadIdx.x;     // 0..2047
  int bh = idx >> 5, c = idx & 31;
  int which = c >> 3, chunk = c & 7;
  short* base = (which < 2) ? q : kk;
  size_t off = (size_t)bh * 1026 * 64 + ((which & 1) ? (size_t)1025 * 64 : 0) + chunk * 8;
  s16x8 zz = {};
  *(s16x8*)&base[off] = zz;
}

// ---------------- all weight transpose-casts in one launch ----------------
DEV void tcast_tile(const float* __restrict__ W, short* __restrict__ Wt, int K, int N, int tx, int ty){
  __shared__ float tile[32][33];
  int nb = tx * 32, kb = ty * 32;
  int tid = threadIdx.x;
  int c = tid & 31, r0 = tid >> 5;
  #pragma unroll
  for (int r = r0; r < 32; r += 8) tile[r][c] = W[(size_t)(kb + r) * N + nb + c];
  __syncthreads();
  #pragma unroll
  for (int r = r0; r < 32; r += 8) Wt[(size_t)(nb + r) * K + kb + c] = f2b(tile[c][r]);
}
__global__ __launch_bounds__(256) void k_tcast_all(const float* __restrict__ Wq, const float* __restrict__ Wk,
                                                   const float* __restrict__ Wv, const float* __restrict__ projW,
                                                   const float* __restrict__ histW, const float* __restrict__ ctxW1,
                                                   short* __restrict__ wqkvt, short* __restrict__ wptb,
                                                   short* __restrict__ whtb, short* __restrict__ wc1tb){
  int bid = blockIdx.x;
  const float* W; short* Wt; int K, N, tx, ty;
  if (bid < 4096) {
    int seg = bid >> 10, t = bid & 1023;
    tx = t & 31; ty = t >> 5; K = 1024; N = 1024;
    if      (seg == 0) { W = Wq;    Wt = wqkvt; }
    else if (seg == 1) { W = Wk;    Wt = wqkvt + 1024*1024; }
    else if (seg == 2) { W = Wv;    Wt = wqkvt + 2*1024*1024; }
    else               { W = projW; Wt = wptb; }
  } else if (bid < 6144) {
    int t = bid - 4096; tx = t & 63; ty = t >> 6; K = 1024; N = 2048; W = histW; Wt = whtb;
  } else {
    int t = bid - 6144; tx = t & 15; ty = t >> 4; K = 2048; N = 512; W = ctxW1; Wt = wc1tb;
  }
  tcast_tile(W, Wt, K, N, tx, ty);
}

// ---------------- GEMM core: per-wave acc = A[m0:m0+128, :K] * Bt[n0:n0+128, :K]^T ----------------
DEV void gemm_core(const short* __restrict__ A, const short* __restrict__ Bt,
                   int K, int lda, int ldb, int m0, int n0,
                   short* lA, short* lB, f32x4 acc[4][4])
{
  const int tid = threadIdx.x;
  const int lane = tid & 63;
  const int w = tid >> 6;
  const int wr = (w >> 1) * 64, wc = (w & 1) * 64;
  const int lr = lane & 15, lk = (lane >> 4) * 8;
  for (int kt = 0; kt < K; kt += 64) {
    __syncthreads();
    #pragma unroll
    for (int i = 0; i < 4; ++i) {
      int off = i * 2048 + tid * 8;
      int r = off >> 6, c = off & 63;
      gload16(&A[(size_t)(m0 + r) * lda + kt + c], &lA[off]);
      gload16(&Bt[(size_t)(n0 + r) * ldb + kt + c], &lB[off]);
    }
    __syncthreads();
    #pragma unroll
    for (int kk = 0; kk < 64; kk += 32) {
      bf16x8 af[4], bfr[4];
      #pragma unroll
      for (int mi = 0; mi < 4; ++mi) af[mi] = *(bf16x8*)&lA[(wr + mi*16 + lr)*64 + kk + lk];
      #pragma unroll
      for (int ni = 0; ni < 4; ++ni) bfr[ni] = *(bf16x8*)&lB[(wc + ni*16 + lr)*64 + kk + lk];
      #pragma unroll
      for (int mi = 0; mi < 4; ++mi)
        #pragma unroll
        for (int ni = 0; ni < 4; ++ni)
          acc[mi][ni] = __builtin_amdgcn_mfma_f32_16x16x32_bf16(af[mi], bfr[ni], acc[mi][ni], 0, 0, 0);
    }
  }
}

// ---------------- GEMM with fp32 output (+bias, optional gelu) ----------------
__global__ __launch_bounds__(256) void k_gemm_f32out(const short* __restrict__ A, const short* __restrict__ Bt,
                                                     float* __restrict__ Cout, const float* __restrict__ bias,
                                                     int N, int K, int doGelu)
{
  __shared__ __align__(16) short lds[2 * 128 * 64];
  f32x4 acc[4][4] = {};
  int bx = blockIdx.x, by = blockIdx.y;
  xy_swz(bx, by, gridDim.x, gridDim.y);
  int m0 = by * 128, n0 = bx * 128;
  gemm_core(A, Bt, K, K, K, m0, n0, lds, lds + 128*64, acc);
  int lane = threadIdx.x & 63, w = threadIdx.x >> 6;
  int wr = (w>>1)*64, wc = (w&1)*64, lr4 = (lane>>4)*4, lc = lane & 15;
  #pragma unroll
  for (int mi = 0; mi < 4; ++mi)
    #pragma unroll
    for (int ni = 0; ni < 4; ++ni)
      #pragma unroll
      for (int r = 0; r < 4; ++r) {
        int row = m0 + wr + mi*16 + lr4 + r;
        int col = n0 + wc + ni*16 + lc;
        float v = acc[mi][ni][r] + bias[col];
        if (doGelu) v = gelu_f(v);
        Cout[(size_t)row * N + col] = v;
      }
}

// ---------------- fused QKV GEMM: x[4096,1024] @ Wqkv^T, heads epilogue ----------------
// q/k written into PADDED [bh][1026][64] layout (row t -> 1+t); v -> vt [bh][64][1024]
__global__ __launch_bounds__(256) void k_gemm_qkv(const short* __restrict__ xb, const short* __restrict__ wqkvt,
                                                  short* __restrict__ q, short* __restrict__ kk, short* __restrict__ vt)
{
  __shared__ __align__(16) short lds[128 * 136];
  f32x4 acc[4][4] = {};
  int bx = blockIdx.x, by = blockIdx.y;
  xy_swz(bx, by, gridDim.x, gridDim.y);
  int m0 = by * 128, n0 = bx * 128;
  gemm_core(xb, wqkvt, 1024, 1024, 1024, m0, n0, lds, lds + 128*64, acc);
  int tid = threadIdx.x, lane = tid & 63, w = tid >> 6;
  int wr = (w>>1)*64, wc = (w&1)*64, lr4 = (lane>>4)*4, lc = lane & 15;
  int bb = m0 >> 10, tm0 = m0 & 1023;
  int s = n0 >> 10, dn0 = n0 & 1023;
  __syncthreads();
  if (s < 2) {
    short* dst = (s == 0) ? q : kk;
    #pragma unroll
    for (int mi = 0; mi < 4; ++mi)
      #pragma unroll
      for (int ni = 0; ni < 4; ++ni)
        #pragma unroll
        for (int r = 0; r < 4; ++r)
          lds[(wr + mi*16 + lr4 + r) * 136 + wc + ni*16 + lc] = f2b(acc[mi][ni][r]);
    __syncthreads();
    #pragma unroll
    for (int it = 0; it < 8; ++it) {
      int idx = it * 256 + tid;
      int row = idx >> 4, ch = (idx & 15) * 8;
      int dfull = dn0 + ch;
      *(s16x8*)&dst[((size_t)(bb*16 + (dfull >> 6)) * 1026 + 1 + tm0 + row) * 64 + (dfull & 63)]
          = *(s16x8*)&lds[row * 136 + ch];
    }
  } else {
    #pragma unroll
    for (int mi = 0; mi < 4; ++mi)
      #pragma unroll
      for (int ni = 0; ni < 4; ++ni)
        #pragma unroll
        for (int r = 0; r < 4; ++r)
          lds[(wc + ni*16 + lc) * 136 + wr + mi*16 + lr4 + r] = f2b(acc[mi][ni][r]);
    __syncthreads();
    #pragma unroll
    for (int it = 0; it < 8; ++it) {
      int idx = it * 256 + tid;
      int nl = idx >> 4, mc = (idx & 15) * 8;
      int dfull = dn0 + nl;
      *(s16x8*)&vt[(((size_t)(bb*16 + (dfull >> 6)) * 64 + (dfull & 63)) << 10) + tm0 + mc]
          = *(s16x8*)&lds[nl * 136 + mc];
    }
  }
}

// ---------------- fused flash attention: QK^T + conv3x3 + softmax + PV ----------------
constexpr int ASTR = 152;   // lS col stride (shorts)

// conv over one 8-col chunk; reads lS rows g..g+2, col idx 8+c-1 .. 8+c+8
DEV void conv_chunk(const short* sS, int g, int c,
                    const h16x2 wp01[3], const h16x2 wp2z[3], float o[8]) {
  #pragma unroll
  for (int dr = 0; dr < 3; ++dr) {
    int base = (g + dr) * ASTR + 8 + c;
    const unsigned* W = (const unsigned*)&sS[base];
    unsigned U0 = W[0], U1 = W[1], U2 = W[2], U3 = W[3];
    unsigned hm1 = (unsigned short)sS[base - 1];
    unsigned hp8 = (unsigned short)sS[base + 8];
    unsigned P0 = hm1 | (U0 << 16);
    unsigned P2 = (U0 >> 16) | (U1 << 16);
    unsigned P4 = (U1 >> 16) | (U2 << 16);
    unsigned P6 = (U2 >> 16) | (U3 << 16);
    unsigned P8 = (U3 >> 16) | (hp8 << 16);
    unsigned P9 = hp8;
    unsigned pr[10] = {P0, U0, P2, U1, P4, U2, P6, U3, P8, P9};
    h16x2 a = wp01[dr], bz = wp2z[dr];
    #pragma unroll
    for (int t = 0; t < 8; ++t) {
      o[t] = __builtin_amdgcn_fdot2(a,  u2h2(pr[t]),     o[t], false);
      o[t] = __builtin_amdgcn_fdot2(bz, u2h2(pr[t + 2]), o[t], false);
    }
  }
}

__global__ __launch_bounds__(512, 4) void k_attn(const short* __restrict__ q, const short* __restrict__ kkg,
                                                 const short* __restrict__ vt, const float* __restrict__ kern,
                                                 short* __restrict__ O)
{
  __shared__ __align__(16) short lQ[130 * 64];   // padded q rows m0 .. m0+129 (= global m0-1 .. m0+128)
  __shared__ __align__(16) short lK[144 * 64];   // padded k rows n0 .. n0+129, zero-filled to 144
  __shared__ __align__(16) short lS[130 * ASTR]; // S (f16); later P (bf16)
  __shared__ float sInv[128];

  int bh = blockIdx.y, b = bh >> 4, h = bh & 15;
  int qt = (bh >= 32) ? 7 - blockIdx.x : blockIdx.x;   // pair heavy+light tiles
  int m0 = qt * 128;
  int tid = threadIdx.x;
  int w = tid >> 6, lane = tid & 63;
  int lr = lane & 15, lk = (lane >> 4) * 8;

  const short* qp = q   + (size_t)bh * 1026 * 64;
  const short* kp = kkg + (size_t)bh * 1026 * 64;

  h16x2 wp01[3], wp2z[3];
  #pragma unroll
  for (int a = 0; a < 3; ++a) {
    wp01[a][0] = (_Float16)kern[bh * 9 + a * 3 + 0];
    wp01[a][1] = (_Float16)kern[bh * 9 + a * 3 + 1];
    wp2z[a][0] = (_Float16)kern[bh * 9 + a * 3 + 2];
    wp2z[a][1] = (_Float16)0.0f;
  }

  s16x8 zz = {};
  // stage Q: 130 rows, padded row index m0+r, branch-free
  for (int t = tid; t < 130 * 8; t += 512)
    gload16(&qp[((size_t)(m0 + (t >> 3))) * 64 + (t & 7) * 8], &lQ[t * 8]);

  f32x4 pacc[4] = {};      // PV accumulator: wave w -> rows w*16.., 4 d-tiles
  float psum = 0.0f;       // partial row-sum for row g = tid>>2 (col quarter qc)
  int g = tid >> 2, qc = tid & 3;

  for (int ct = 0; ct <= qt; ++ct) {
    int n0 = ct * 128;
    // ---- stage K: 130 rows branch-free; rows 130..143 zero (pure stores) ----
    for (int t = tid; t < 130 * 8; t += 512)
      gload16(&kp[((size_t)(n0 + (t >> 3))) * 64 + (t & 7) * 8], &lK[t * 8]);
    for (int t = tid; t < 14 * 8; t += 512)
      *(s16x8*)&lK[(130 * 8 + t) * 8] = zz;
    __syncthreads();   // lK/lQ ready; previous PV done with lS

    // ---- QK^T: wave w owns inner-row tile w (rows m0+w*16 ..+15) ----
    int ntmax = (ct == qt) ? (w + 2) : 9;
    for (int nt = 0; nt < ntmax; ++nt) {
      f32x4 acc = {};
      #pragma unroll
      for (int kk = 0; kk < 64; kk += 32) {
        bf16x8 aq = *(bf16x8*)&lQ[(1 + w * 16 + lr) * 64 + kk + lk];
        bf16x8 bk = *(bf16x8*)&lK[(nt * 16 + lr) * 64 + kk + lk];
        acc = __builtin_amdgcn_mfma_f32_16x16x32_bf16(aq, bk, acc, 0, 0, 0);
      }
      int cloc = nt * 16 + lr - 1;           // global col = n0 + cloc
      if (cloc <= 128) {
        #pragma unroll
        for (int r = 0; r < 4; ++r) {
          int rl = w * 16 + (lane >> 4) * 4 + r;   // inner row
          float v = acc[r] * 0.125f;
          if (n0 + cloc > m0 + rl) v = 0.0f;
          lS[(rl + 1) * ASTR + 8 + cloc] = f2h(v);
        }
      }
    }
    // ---- halo rows m0-1 (lS row 0) and m0+128 (lS row 129): VALU dots ----
    {
      int hr = -1, hl = 0;
      if (tid < 130) { hr = 0; hl = tid; }
      else if (tid >= 256 && tid < 386) { hr = 129; hl = tid - 256; }
      if (hr >= 0) {
        int cloc = hl - 1;
        int gq = m0 - 1 + hr;
        int gk = n0 + cloc;
        float s = 0.0f;
        if (gq >= 0 && gq < 1024 && gk >= 0 && gk <= gq) {
          #pragma unroll
          for (int kk2 = 0; kk2 < 64; kk2 += 8) {
            s16x8 qv = *(s16x8*)&lQ[hr * 64 + kk2];
            s16x8 kv = *(s16x8*)&lK[(cloc + 1) * 64 + kk2];
            #pragma unroll
            for (int j = 0; j < 8; ++j) s += b2f(qv[j]) * b2f(kv[j]);
          }
          s *= 0.125f;
        }
        lS[hr * ASTR + 8 + cloc] = f2h(s);
      }
    }
    __syncthreads();   // S tile complete

    // ---- conv + exp: thread (g, qc) -> row g, cols qc*32..+31 ----
    s16x8 ps[4];
    #pragma unroll
    for (int j = 0; j < 4; ++j) {
      int c = qc * 32 + j * 8;
      bool live = (ct < qt) || (c <= g);
      float o[8] = {};
      if (live) conv_chunk(lS, g, c, wp01, wp2z, o);
      int glim = (ct == qt) ? g : 127;
      s16x8 po;
      #pragma unroll
      for (int t = 0; t < 8; ++t) {
        float e = (live && (c + t <= glim)) ? __expf(o[t]) : 0.0f;
        psum += e;
        po[t] = f2b(e);
      }
      ps[j] = po;
    }
    __syncthreads();   // conv reads done; safe to overwrite lS with P

    #pragma unroll
    for (int j = 0; j < 4; ++j)
      *(s16x8*)&lS[g * ASTR + 8 + qc * 32 + j * 8] = ps[j];
    __syncthreads();   // P ready

    // ---- PV: wave w -> out rows w*16..+15, 4 d-tiles of 16 ----
    int kl = 128;
    if (ct == qt) { kl = ((w * 16 + 16 + 31) >> 5) << 5; if (kl > 128) kl = 128; }
    for (int k0 = 0; k0 < kl; k0 += 32) {
      bf16x8 a = *(bf16x8*)&lS[(w * 16 + lr) * ASTR + 8 + k0 + lk];
      #pragma unroll
      for (int dt = 0; dt < 4; ++dt) {
        bf16x8 bv = *(const bf16x8*)&vt[(((size_t)bh * 64 + dt * 16 + lr) << 10) + n0 + k0 + lk];
        pacc[dt] = __builtin_amdgcn_mfma_f32_16x16x32_bf16(a, bv, pacc[dt], 0, 0, 0);
      }
    }
  }

  // ---- epilogue ----
  psum += __shfl_xor(psum, 1);
  psum += __shfl_xor(psum, 2);
  if (qc == 0) sInv[g] = 1.0f / psum;
  __syncthreads();
  #pragma unroll
  for (int dt = 0; dt < 4; ++dt)
    #pragma unroll
    for (int r = 0; r < 4; ++r) {
      int row = w * 16 + (lane >> 4) * 4 + r;
      float ov = pacc[dt][r] * sInv[row];
      O[((size_t)(b * 1024 + m0 + row) << 10) + h * 64 + dt * 16 + lr] = f2b(ov);
    }
}

// ---------------- LN + gelu, fp32[*,2048] -> bf16, vectorized ----------------
__global__ __launch_bounds__(256) void k_ln_gelu2048(const float* __restrict__ x, const float* __restrict__ g,
                                                     const float* __restrict__ be, short* __restrict__ out)
{
  __shared__ float red[8];
  int row = blockIdx.x, tid = threadIdx.x;
  const float* xr = x + (size_t)row * 2048;
  int c0 = tid * 8;
  f32x4 a = *(const f32x4*)&xr[c0];
  f32x4 bb = *(const f32x4*)&xr[c0 + 4];
  float s = 0, s2 = 0;
  #pragma unroll
  for (int t = 0; t < 4; ++t) { s += a[t] + bb[t]; s2 += a[t]*a[t] + bb[t]*bb[t]; }
  #pragma unroll
  for (int off = 32; off; off >>= 1) { s += __shfl_xor(s, off); s2 += __shfl_xor(s2, off); }
  if ((tid & 63) == 0) { red[tid >> 6] = s; red[4 + (tid >> 6)] = s2; }
  __syncthreads();
  s  = red[0] + red[1] + red[2] + red[3];
  s2 = red[4] + red[5] + red[6] + red[7];
  float mean = s * (1.0f / 2048.0f);
  float var  = s2 * (1.0f / 2048.0f) - mean * mean;
  float inv  = rsqrtf(var + 1e-5f);
  f32x4 g0 = *(const f32x4*)&g[c0],  g1 = *(const f32x4*)&g[c0 + 4];
  f32x4 e0 = *(const f32x4*)&be[c0], e1 = *(const f32x4*)&be[c0 + 4];
  s16x8 o;
  #pragma unroll
  for (int t = 0; t < 4; ++t) {
    o[t]     = f2b(gelu_f((a[t]  - mean) * inv * g0[t] + e0[t]));
    o[t + 4] = f2b(gelu_f((bb[t] - mean) * inv * g1[t] + e1[t]));
  }
  *(s16x8*)&out[(size_t)row * 2048 + c0] = o;
}

// ---------------- aw logits: t[1024,512] . w2[512] + b2 (one wave per row) ----------------
__global__ __launch_bounds__(256) void k_aw_logit(const float* __restrict__ t, const float* __restrict__ w2,
                                                  const float* __restrict__ b2, float* __restrict__ logit)
{
  int row = blockIdx.x * 4 + (threadIdx.x >> 6);
  int lane = threadIdx.x & 63;
  float s = 0;
  for (int c = lane; c < 512; c += 64) s += t[(size_t)row * 512 + c] * w2[c];
  #pragma unroll
  for (int off = 32; off; off >>= 1) s += __shfl_xor(s, off);
  if (lane == 0) logit[row] = s + b2[0];
}

// ---------------- softmax (redundant per block) + weighted pool: block (cchunk, b) ----------------
__global__ __launch_bounds__(256) void k_softmax_cc(const float* __restrict__ logit, const short* __restrict__ ehb,
                                                    float* __restrict__ cc)
{
  __shared__ float sw[256];
  __shared__ float red[8];
  int b = blockIdx.y, ch = blockIdx.x, tid = threadIdx.x;
  float v = logit[b * 256 + tid];
  float m = v;
  #pragma unroll
  for (int off = 32; off; off >>= 1) m = fmaxf(m, __shfl_xor(m, off));
  if ((tid & 63) == 0) red[tid >> 6] = m;
  __syncthreads();
  float M = fmaxf(fmaxf(red[0], red[1]), fmaxf(red[2], red[3]));
  float e = __expf(v - M);
  float s = e;
  #pragma unroll
  for (int off = 32; off; off >>= 1) s += __shfl_xor(s, off);
  if ((tid & 63) == 0) red[4 + (tid >> 6)] = s;
  __syncthreads();
  float invS = 1.0f / (red[4] + red[5] + red[6] + red[7]);
  sw[tid] = e * invS;
  __syncthreads();
  int c = ch * 256 + tid;
  float a = 0;
  for (int t = 0; t < 256; ++t) a += sw[t] * b2f(ehb[(((size_t)(b * 256 + t)) << 11) + c]);
  cc[(b << 11) + c] = a;
}

// ---------------- kg1 split-K partials: 128 blocks ----------------
__global__ __launch_bounds__(256) void k_kg1p(const float* __restrict__ cc, const float* __restrict__ W1,
                                              float* __restrict__ part)
{
  int d = blockIdx.x * 256 + threadIdx.x;
  int kc = blockIdx.y;
  float s0 = 0, s1 = 0, s2 = 0, s3 = 0;
  for (int k = kc * 64; k < kc * 64 + 64; ++k) {
    float w = W1[(size_t)k * 1024 + d];
    s0 += cc[k] * w; s1 += cc[2048 + k] * w; s2 += cc[4096 + k] * w; s3 += cc[6144 + k] * w;
  }
  part[(size_t)(kc * 4 + 0) * 1024 + d] = s0;
  part[(size_t)(kc * 4 + 1) * 1024 + d] = s1;
  part[(size_t)(kc * 4 + 2) * 1024 + d] = s2;
  part[(size_t)(kc * 4 + 3) * 1024 + d] = s3;
}

// ---------------- kg mid: reduce partials + bias, LN, gelu -> kgh bf16 ----------------
__global__ __launch_bounds__(256) void k_kg_mid(const float* __restrict__ part, const float* __restrict__ b1,
                                                const float* __restrict__ g, const float* __restrict__ be,
                                                short* __restrict__ kgh)
{
  __shared__ float red[8];
  int b = blockIdx.x, tid = threadIdx.x;
  float v[4]; float s = 0, s2 = 0;
  #pragma unroll
  for (int qi = 0; qi < 4; ++qi) {
    int d = tid + qi * 256;
    float acc = b1[d];
    for (int kc = 0; kc < 32; ++kc) acc += part[(size_t)(kc * 4 + b) * 1024 + d];
    v[qi] = acc; s += acc; s2 += acc * acc;
  }
  #pragma unroll
  for (int off = 32; off; off >>= 1) { s += __shfl_xor(s, off); s2 += __shfl_xor(s2, off); }
  if ((tid & 63) == 0) { red[tid >> 6] = s; red[4 + (tid >> 6)] = s2; }
  __syncthreads();
  s  = red[0] + red[1] + red[2] + red[3];
  s2 = red[4] + red[5] + red[6] + red[7];
  float mean = s * (1.0f / 1024.0f);
  float var  = s2 * (1.0f / 1024.0f) - mean * mean;
  float inv  = rsqrtf(var + 1e-5f);
  #pragma unroll
  for (int qi = 0; qi < 4; ++qi) {
    int d = tid + qi * 256;
    kgh[b * 1024 + d] = f2b(gelu_f((v[qi] - mean) * inv * g[d] + be[d]));
  }
}

// ---------------- kp + softmax9: one wave per (h,b) ----------------
__global__ __launch_bounds__(64) void k_kp2(const short* __restrict__ kgh, const float* __restrict__ W2,
                                            const float* __restrict__ b2, float* __restrict__ kern)
{
  int h = blockIdx.x, b = blockIdx.y, lane = threadIdx.x;
  float kg[16];
  #pragma unroll
  for (int m = 0; m < 16; ++m) kg[m] = b2f(kgh[b * 1024 + lane + m * 64]);
  float dj[9];
  #pragma unroll
  for (int j = 0; j < 9; ++j) {
    float s = 0;
    #pragma unroll
    for (int m = 0; m < 16; ++m) s += kg[m] * W2[(size_t)(lane + m * 64) * 144 + h * 9 + j];
    #pragma unroll
    for (int off = 32; off; off >>= 1) s += __shfl_xor(s, off);
    dj[j] = s + b2[h * 9 + j];
  }
  if (lane == 0) {
    float m = dj[0];
    #pragma unroll
    for (int j = 1; j < 9; ++j) m = fmaxf(m, dj[j]);
    float e[9], s = 0;
    #pragma unroll
    for (int j = 0; j < 9; ++j) { e[j] = __expf(dj[j] - m); s += e[j]; }
    float inv = 1.0f / s;
    #pragma unroll
    for (int j = 0; j < 9; ++j) kern[(b * 16 + h) * 9 + j] = e[j] * inv;
  }
}

__global__ void k_fail(float* out){ out[threadIdx.x] = 1.0e9f; }

extern "C" void kernel_launch(void* const* d_in, const int* in_sizes, int n_in,
                              void* d_out, int out_size, void* d_ws, size_t ws_size,
                              hipStream_t stream) {
  (void)in_sizes; (void)n_in; (void)out_size;
  const float* x       = (const float*)d_in[0];
  const float* hist    = (const float*)d_in[1];
  const float* Wq      = (const float*)d_in[2];
  const float* Wk      = (const float*)d_in[3];
  const float* Wv      = (const float*)d_in[4];
  const float* hist_W  = (const float*)d_in[5];
  const float* hist_b  = (const float*)d_in[6];
  const float* hln_g   = (const float*)d_in[7];
  const float* hln_b   = (const float*)d_in[8];
  const float* ctx_W1  = (const float*)d_in[9];
  const float* ctx_b1  = (const float*)d_in[10];
  const float* ctx_W2  = (const float*)d_in[11];
  const float* ctx_b2  = (const float*)d_in[12];
  const float* kg_W1   = (const float*)d_in[13];
  const float* kg_b1   = (const float*)d_in[14];
  const float* kln_g   = (const float*)d_in[15];
  const float* kln_b   = (const float*)d_in[16];
  const float* kg_W2   = (const float*)d_in[17];
  const float* kg_b2   = (const float*)d_in[18];
  const float* proj_W  = (const float*)d_in[19];
  const float* proj_b  = (const float*)d_in[20];
  float* outp = (float*)d_out;

  char* wsb = (char*)d_ws;
  size_t off = 0;
  auto nxt = [&](size_t bytes) { void* p = wsb + off; off += (bytes + 255) & ~(size_t)255; return p; };

  short* xb     = (short*)nxt((size_t)4096*1024*2);
  short* wqkvt  = (short*)nxt((size_t)3*1024*1024*2);
  short* qb     = (short*)nxt((size_t)64*1026*64*2);   // padded
  short* kb     = (short*)nxt((size_t)64*1026*64*2);   // padded
  short* vtb    = (short*)nxt((size_t)64*64*1024*2);
  short* Ob     = (short*)nxt((size_t)4096*1024*2);
  short* histb  = (short*)nxt((size_t)1024*1024*2);
  short* whtb   = (short*)nxt((size_t)2048*1024*2);
  float* ehpre  = (float*)nxt((size_t)1024*2048*4);
  short* ehb    = (short*)nxt((size_t)1024*2048*2);
  short* wc1tb  = (short*)nxt((size_t)512*2048*2);
  float* tbuf   = (float*)nxt((size_t)1024*512*4);
  float* logit  = (float*)nxt((size_t)1024*4);
  float* ccb    = (float*)nxt((size_t)4*2048*4);
  float* kgpart = (float*)nxt((size_t)128*1024*4);
  short* kghb   = (short*)nxt((size_t)4*1024*2);
  float* kernb  = (float*)nxt((size_t)64*9*4);
  short* wptb   = (short*)nxt((size_t)1024*1024*2);

  if (ws_size < off) { k_fail<<<1, 64, 0, stream>>>(outp); return; }

  // casts + weight transposes + pad zeroing
  k_cast_all<<<2560, 256, 0, stream>>>(x, hist, xb, histb);
  k_zero_qk_pads<<<8, 256, 0, stream>>>(qb, kb);
  k_tcast_all<<<7168, 256, 0, stream>>>(Wq, Wk, Wv, proj_W, hist_W, ctx_W1, wqkvt, wptb, whtb, wc1tb);

  // context path
  k_gemm_f32out<<<dim3(16, 8), 256, 0, stream>>>(histb, whtb, ehpre, hist_b, 2048, 1024, 0);
  k_ln_gelu2048<<<1024, 256, 0, stream>>>(ehpre, hln_g, hln_b, ehb);
  k_gemm_f32out<<<dim3(4, 8), 256, 0, stream>>>(ehb, wc1tb, tbuf, ctx_b1, 512, 2048, 1);
  k_aw_logit<<<256, 256, 0, stream>>>(tbuf, ctx_W2, ctx_b2, logit);
  k_softmax_cc<<<dim3(8, 4), 256, 0, stream>>>(logit, ehb, ccb);
  k_kg1p<<<dim3(4, 32), 256, 0, stream>>>(ccb, kg_W1, kgpart);
  k_kg_mid<<<4, 256, 0, stream>>>(kgpart, kg_b1, kln_g, kln_b, kghb);
  k_kp2<<<dim3(16, 4), 64, 0, stream>>>(kghb, kg_W2, kg_b2, kernb);

  // attention path
  k_gemm_qkv<<<dim3(24, 32), 256, 0, stream>>>(xb, wqkvt, qb, kb, vtb);
  k_attn<<<dim3(8, 64), 512, 0, stream>>>(qb, kb, vtb, kernb, Ob);
  k_gemm_f32out<<<dim3(8, 32), 256, 0, stream>>>(Ob, wptb, outp, proj_b, 1024, 1024, 0);
}

// Round 8
// 280.910 us; speedup vs baseline: 1.2467x; 1.1054x over previous
//
#include <hip/hip_runtime.h>
#include <hip/hip_bf16.h>
#include <math.h>

#define DEV static __device__ __forceinline__

typedef __attribute__((ext_vector_type(4))) float f32x4;
typedef __attribute__((ext_vector_type(8))) __bf16 bf16x8;
typedef __attribute__((ext_vector_type(8))) short s16x8;
typedef __attribute__((ext_vector_type(2))) _Float16 h16x2;

DEV float b2f(short v){ unsigned u = ((unsigned)(unsigned short)v) << 16; float f; __builtin_memcpy(&f, &u, 4); return f; }
DEV short f2b(float f){ unsigned u; __builtin_memcpy(&u, &f, 4); unsigned r = (u + 0x7fffu + ((u >> 16) & 1u)) >> 16; return (short)r; }
DEV short f2h(float f){ _Float16 h = (_Float16)f; short s; __builtin_memcpy(&s, &h, 2); return s; }
DEV h16x2 u2h2(unsigned u){ h16x2 h; __builtin_memcpy(&h, &u, 4); return h; }
DEV float gelu_f(float v){ return 0.5f * v * (1.0f + erff(v * 0.70710678118654752f)); }

DEV void gload16(const void* g, void* l) {
  __builtin_amdgcn_global_load_lds((const __attribute__((address_space(1))) unsigned int*)g,
                                   (__attribute__((address_space(3))) unsigned int*)l, 16, 0, 0);
}

// XCD-bijective swizzle over a 2D grid (requires nx*ny % 8 == 0)
DEV void xy_swz(int& bx, int& by, int nx, int ny) {
  int lin = by * nx + bx;
  int q = (nx * ny) >> 3;
  int l2 = (lin & 7) * q + (lin >> 3);
  bx = l2 % nx; by = l2 / nx;
}

// ---------------- fused cast fp32 -> bf16 for x and hist + q/k pad-row zeroing ----------------
__global__ __launch_bounds__(256) void k_cast_all(const float* __restrict__ x, const float* __restrict__ hist,
                                                  short* __restrict__ xb, short* __restrict__ histb,
                                                  short* __restrict__ q, short* __restrict__ kk){
  int bid = blockIdx.x;
  if (bid >= 2560) {              // zero pad rows 0 and 1025 of padded q/k
    int idx = (bid - 2560) * 256 + threadIdx.x;   // 0..2047
    int bh = idx >> 5, c = idx & 31;
    int which = c >> 3, chunk = c & 7;
    short* base = (which < 2) ? q : kk;
    size_t off = (size_t)bh * 1026 * 64 + ((which & 1) ? (size_t)1025 * 64 : 0) + chunk * 8;
    s16x8 zz = {};
    *(s16x8*)&base[off] = zz;
    return;
  }
  const float* in; short* out; int i;
  if (bid < 2048) { in = x; out = xb; i = (bid * 256 + threadIdx.x) * 8; }
  else            { in = hist; out = histb; i = ((bid - 2048) * 256 + threadIdx.x) * 8; }
  f32x4 a = *(const f32x4*)&in[i];
  f32x4 b = *(const f32x4*)&in[i + 4];
  s16x8 o;
  o[0]=f2b(a[0]); o[1]=f2b(a[1]); o[2]=f2b(a[2]); o[3]=f2b(a[3]);
  o[4]=f2b(b[0]); o[5]=f2b(b[1]); o[6]=f2b(b[2]); o[7]=f2b(b[3]);
  *(s16x8*)&out[i] = o;
}

// ---------------- all weight transpose-casts in one launch ----------------
DEV void tcast_tile(const float* __restrict__ W, short* __restrict__ Wt, int K, int N, int tx, int ty){
  __shared__ float tile[32][33];
  int nb = tx * 32, kb = ty * 32;
  int tid = threadIdx.x;
  int c = tid & 31, r0 = tid >> 5;
  #pragma unroll
  for (int r = r0; r < 32; r += 8) tile[r][c] = W[(size_t)(kb + r) * N + nb + c];
  __syncthreads();
  #pragma unroll
  for (int r = r0; r < 32; r += 8) Wt[(size_t)(nb + r) * K + kb + c] = f2b(tile[c][r]);
}
__global__ __launch_bounds__(256) void k_tcast_all(const float* __restrict__ Wq, const float* __restrict__ Wk,
                                                   const float* __restrict__ Wv, const float* __restrict__ projW,
                                                   const float* __restrict__ histW, const float* __restrict__ ctxW1,
                                                   short* __restrict__ wqkvt, short* __restrict__ wptb,
                                                   short* __restrict__ whtb, short* __restrict__ wc1tb){
  int bid = blockIdx.x;
  const float* W; short* Wt; int K, N, tx, ty;
  if (bid < 4096) {
    int seg = bid >> 10, t = bid & 1023;
    tx = t & 31; ty = t >> 5; K = 1024; N = 1024;
    if      (seg == 0) { W = Wq;    Wt = wqkvt; }
    else if (seg == 1) { W = Wk;    Wt = wqkvt + 1024*1024; }
    else if (seg == 2) { W = Wv;    Wt = wqkvt + 2*1024*1024; }
    else               { W = projW; Wt = wptb; }
  } else if (bid < 6144) {
    int t = bid - 4096; tx = t & 63; ty = t >> 6; K = 1024; N = 2048; W = histW; Wt = whtb;
  } else {
    int t = bid - 6144; tx = t & 15; ty = t >> 4; K = 2048; N = 512; W = ctxW1; Wt = wc1tb;
  }
  tcast_tile(W, Wt, K, N, tx, ty);
}

// ---------------- GEMM core: per-wave acc = A[m0:m0+128, kt..kt+Ks] * Bt[n0:n0+128, ...]^T ----------------
DEV void gemm_core(const short* __restrict__ A, const short* __restrict__ Bt,
                   int Ks, int lda, int ldb, int m0, int n0,
                   short* lA, short* lB, f32x4 acc[4][4])
{
  const int tid = threadIdx.x;
  const int lane = tid & 63;
  const int w = tid >> 6;
  const int wr = (w >> 1) * 64, wc = (w & 1) * 64;
  const int lr = lane & 15, lk = (lane >> 4) * 8;
  for (int kt = 0; kt < Ks; kt += 64) {
    __syncthreads();
    #pragma unroll
    for (int i = 0; i < 4; ++i) {
      int off = i * 2048 + tid * 8;
      int r = off >> 6, c = off & 63;
      gload16(&A[(size_t)(m0 + r) * lda + kt + c], &lA[off]);
      gload16(&Bt[(size_t)(n0 + r) * ldb + kt + c], &lB[off]);
    }
    __syncthreads();
    #pragma unroll
    for (int kk = 0; kk < 64; kk += 32) {
      bf16x8 af[4], bfr[4];
      #pragma unroll
      for (int mi = 0; mi < 4; ++mi) af[mi] = *(bf16x8*)&lA[(wr + mi*16 + lr)*64 + kk + lk];
      #pragma unroll
      for (int ni = 0; ni < 4; ++ni) bfr[ni] = *(bf16x8*)&lB[(wc + ni*16 + lr)*64 + kk + lk];
      #pragma unroll
      for (int mi = 0; mi < 4; ++mi)
        #pragma unroll
        for (int ni = 0; ni < 4; ++ni)
          acc[mi][ni] = __builtin_amdgcn_mfma_f32_16x16x32_bf16(af[mi], bfr[ni], acc[mi][ni], 0, 0, 0);
    }
  }
}

// ---------------- GEMM, fp32 out; mode 0: +bias, 1: +bias+gelu, 2: raw split-K partial ----------------
__global__ __launch_bounds__(256) void k_gemm_f32out(const short* __restrict__ A, const short* __restrict__ Bt,
                                                     float* __restrict__ Cout, const float* __restrict__ bias,
                                                     int N, int lda, int Ks, int mode)
{
  __shared__ __align__(16) short lds[2 * 128 * 64];
  f32x4 acc[4][4] = {};
  int bx = blockIdx.x, by = blockIdx.y;
  xy_swz(bx, by, gridDim.x, gridDim.y);
  int m0 = by * 128, n0 = bx * 128;
  int koff = blockIdx.z * Ks;
  gemm_core(A + koff, Bt + koff, Ks, lda, lda, m0, n0, lds, lds + 128*64, acc);
  Cout += (size_t)blockIdx.z * gridDim.y * 128 * N;
  int lane = threadIdx.x & 63, w = threadIdx.x >> 6;
  int wr = (w>>1)*64, wc = (w&1)*64, lr4 = (lane>>4)*4, lc = lane & 15;
  #pragma unroll
  for (int mi = 0; mi < 4; ++mi)
    #pragma unroll
    for (int ni = 0; ni < 4; ++ni)
      #pragma unroll
      for (int r = 0; r < 4; ++r) {
        int row = m0 + wr + mi*16 + lr4 + r;
        int col = n0 + wc + ni*16 + lc;
        float v = acc[mi][ni][r];
        if (mode != 2) v += bias[col];
        if (mode == 1) v = gelu_f(v);
        Cout[(size_t)row * N + col] = v;
      }
}

// ---------------- fused QKV GEMM: x[4096,1024] @ Wqkv^T, heads epilogue ----------------
__global__ __launch_bounds__(256) void k_gemm_qkv(const short* __restrict__ xb, const short* __restrict__ wqkvt,
                                                  short* __restrict__ q, short* __restrict__ kk, short* __restrict__ vt)
{
  __shared__ __align__(16) short lds[128 * 136];
  f32x4 acc[4][4] = {};
  int bx = blockIdx.x, by = blockIdx.y;
  xy_swz(bx, by, gridDim.x, gridDim.y);
  int m0 = by * 128, n0 = bx * 128;
  gemm_core(xb, wqkvt, 1024, 1024, 1024, m0, n0, lds, lds + 128*64, acc);
  int tid = threadIdx.x, lane = tid & 63, w = tid >> 6;
  int wr = (w>>1)*64, wc = (w&1)*64, lr4 = (lane>>4)*4, lc = lane & 15;
  int bb = m0 >> 10, tm0 = m0 & 1023;
  int s = n0 >> 10, dn0 = n0 & 1023;
  __syncthreads();
  if (s < 2) {
    short* dst = (s == 0) ? q : kk;
    #pragma unroll
    for (int mi = 0; mi < 4; ++mi)
      #pragma unroll
      for (int ni = 0; ni < 4; ++ni)
        #pragma unroll
        for (int r = 0; r < 4; ++r)
          lds[(wr + mi*16 + lr4 + r) * 136 + wc + ni*16 + lc] = f2b(acc[mi][ni][r]);
    __syncthreads();
    #pragma unroll
    for (int it = 0; it < 8; ++it) {
      int idx = it * 256 + tid;
      int row = idx >> 4, ch = (idx & 15) * 8;
      int dfull = dn0 + ch;
      *(s16x8*)&dst[((size_t)(bb*16 + (dfull >> 6)) * 1026 + 1 + tm0 + row) * 64 + (dfull & 63)]
          = *(s16x8*)&lds[row * 136 + ch];
    }
  } else {
    #pragma unroll
    for (int mi = 0; mi < 4; ++mi)
      #pragma unroll
      for (int ni = 0; ni < 4; ++ni)
        #pragma unroll
        for (int r = 0; r < 4; ++r)
          lds[(wc + ni*16 + lc) * 136 + wr + mi*16 + lr4 + r] = f2b(acc[mi][ni][r]);
    __syncthreads();
    #pragma unroll
    for (int it = 0; it < 8; ++it) {
      int idx = it * 256 + tid;
      int nl = idx >> 4, mc = (idx & 15) * 8;
      int dfull = dn0 + nl;
      *(s16x8*)&vt[(((size_t)(bb*16 + (dfull >> 6)) * 64 + (dfull & 63)) << 10) + tm0 + mc]
          = *(s16x8*)&lds[nl * 136 + mc];
    }
  }
}

// ---------------- fused flash attention: QK^T + conv3x3 + softmax + PV ----------------
constexpr int ASTR = 144;   // lS col stride (shorts); 288B rows

// conv over one 8-col chunk; reads lS rows g..g+2, col idx 8+c-1 .. 8+c+8
DEV void conv_chunk(const short* sS, int g, int c,
                    const h16x2 wp01[3], const h16x2 wp2z[3], float o[8]) {
  #pragma unroll
  for (int dr = 0; dr < 3; ++dr) {
    int base = (g + dr) * ASTR + 8 + c;
    const unsigned* W = (const unsigned*)&sS[base];
    unsigned U0 = W[0], U1 = W[1], U2 = W[2], U3 = W[3];
    unsigned hm1 = (unsigned short)sS[base - 1];
    unsigned hp8 = (unsigned short)sS[base + 8];
    unsigned P0 = hm1 | (U0 << 16);
    unsigned P2 = (U0 >> 16) | (U1 << 16);
    unsigned P4 = (U1 >> 16) | (U2 << 16);
    unsigned P6 = (U2 >> 16) | (U3 << 16);
    unsigned P8 = (U3 >> 16) | (hp8 << 16);
    unsigned P9 = hp8;
    unsigned pr[10] = {P0, U0, P2, U1, P4, U2, P6, U3, P8, P9};
    h16x2 a = wp01[dr], bz = wp2z[dr];
    #pragma unroll
    for (int t = 0; t < 8; ++t) {
      o[t] = __builtin_amdgcn_fdot2(a,  u2h2(pr[t]),     o[t], false);
      o[t] = __builtin_amdgcn_fdot2(bz, u2h2(pr[t + 2]), o[t], false);
    }
  }
}

__global__ __launch_bounds__(512, 4) void k_attn(const short* __restrict__ q, const short* __restrict__ kkg,
                                                 const short* __restrict__ vt, const float* __restrict__ kern,
                                                 short* __restrict__ O)
{
  // lK: chunk-swizzled: row r, 16B-chunk c holds global chunk (c ^ (r&7)); written via
  // pre-swizzled global source + linear LDS dest (global_load_lds constraint).
  __shared__ __align__(16) short lK[2][144 * 64];
  __shared__ __align__(16) short lS[130 * ASTR];
  __shared__ float sInv[128];

  int bh = blockIdx.y, b = bh >> 4, h = bh & 15;
  int qt = (bh >= 32) ? 7 - blockIdx.x : blockIdx.x;   // pair heavy+light tiles
  int m0 = qt * 128;
  int tid = threadIdx.x;
  int w = tid >> 6, lane = tid & 63;
  int lr = lane & 15, lk = (lane >> 4) * 8;

  const short* qp = q   + (size_t)bh * 1026 * 64;
  const short* kp = kkg + (size_t)bh * 1026 * 64;

  h16x2 wp01[3], wp2z[3];
  #pragma unroll
  for (int a = 0; a < 3; ++a) {
    wp01[a][0] = (_Float16)kern[bh * 9 + a * 3 + 0];
    wp01[a][1] = (_Float16)kern[bh * 9 + a * 3 + 1];
    wp2z[a][0] = (_Float16)kern[bh * 9 + a * 3 + 2];
    wp2z[a][1] = (_Float16)0.0f;
  }

  // Q fragment in registers (wave w rows m0+w*16..+15, padded idx +1)
  bf16x8 qf0, qf1;
  {
    const short* qrow = &qp[(size_t)(m0 + 1 + w * 16 + lr) * 64];
    qf0 = *(const bf16x8*)&qrow[lk];
    qf1 = *(const bf16x8*)&qrow[32 + lk];
  }
  // halo thread role
  int hr = -1, hl = 0;
  if (tid < 130) { hr = 0; hl = tid; }
  else if (tid >= 256 && tid < 386) { hr = 129; hl = tid - 256; }

  s16x8 zz = {};
  // zero lK rows 130..143 (both buffers, persists)
  for (int t = tid; t < 14 * 8; t += 512) {
    *(s16x8*)&lK[0][(130 * 8 + t) * 8] = zz;
    *(s16x8*)&lK[1][(130 * 8 + t) * 8] = zz;
  }
  // stage K(ct=0) into buf 0: dest linear chunk t (8 shorts each), source chunk (t&7)^(row&7)
  for (int t = tid; t < 130 * 8; t += 512) {
    int r = t >> 3;
    gload16(&kp[((size_t)r) * 64 + (((t & 7) ^ (r & 7)) << 3)], &lK[0][t * 8]);
  }

  f32x4 pacc[4] = {};
  float psum = 0.0f;
  int g = tid >> 2, qc = tid & 3;
  int cur = 0;

  for (int ct = 0; ct <= qt; ++ct) {
    int n0 = ct * 128;
    __syncthreads();   // staged K(ct) landed (compiler drains vmcnt); prev PV done with lS
    if (ct < qt) {     // prefetch K(ct+1) into other buffer — overlaps QK^T/halo
      int n1 = n0 + 128;
      for (int t = tid; t < 130 * 8; t += 512) {
        int r = t >> 3;
        gload16(&kp[((size_t)(n1 + r)) * 64 + (((t & 7) ^ (r & 7)) << 3)], &lK[cur ^ 1][t * 8]);
      }
    }
    const short* lKc = lK[cur];

    // ---- QK^T: wave w rows m0+w*16..+15; reads swizzled lK chunks ----
    int ntmax = (ct == qt) ? (w + 2) : 9;
    int G0 = lk >> 3;
    for (int nt = 0; nt < ntmax; ++nt) {
      int krow = nt * 16 + lr;
      int sw = (krow & 7) << 3;
      bf16x8 bk0 = *(bf16x8*)&lKc[krow * 64 + (( G0      << 3) ^ sw)];
      bf16x8 bk1 = *(bf16x8*)&lKc[krow * 64 + (((G0 + 4) << 3) ^ sw)];
      f32x4 acc = {};
      acc = __builtin_amdgcn_mfma_f32_16x16x32_bf16(qf0, bk0, acc, 0, 0, 0);
      acc = __builtin_amdgcn_mfma_f32_16x16x32_bf16(qf1, bk1, acc, 0, 0, 0);
      int cloc = nt * 16 + lr - 1;
      if (cloc <= 128) {
        #pragma unroll
        for (int r = 0; r < 4; ++r) {
          int rl = w * 16 + (lane >> 4) * 4 + r;
          float v = acc[r] * 0.125f;
          if (n0 + cloc > m0 + rl) v = 0.0f;
          lS[(rl + 1) * ASTR + 8 + cloc] = f2h(v);
        }
      }
    }
    // ---- halo rows (lS rows 0 and 129): VALU dots; q from global (L1), k from lK ----
    if (hr >= 0) {
      int cloc = hl - 1;
      float s = 0.0f;
      if (n0 + cloc <= m0 - 1 + hr) {      // causal; pad rows of q are zero anyway
        const short* qrow = &qp[(size_t)(m0 + hr) * 64];
        int krow = cloc + 1;
        int swh = (krow & 7) << 3;
        #pragma unroll
        for (int G = 0; G < 8; ++G) {
          s16x8 qv = *(const s16x8*)&qrow[G * 8];
          s16x8 kv = *(const s16x8*)&lKc[krow * 64 + ((G << 3) ^ swh)];
          #pragma unroll
          for (int j = 0; j < 8; ++j) s += b2f(qv[j]) * b2f(kv[j]);
        }
        s *= 0.125f;
      }
      lS[hr * ASTR + 8 + cloc] = f2h(s);
    }
    __syncthreads();   // S tile complete

    // ---- conv + exp: thread (g, qc) -> row g, 16B chunks at cols qc*8 + j*32 ----
    s16x8 ps[4];
    #pragma unroll
    for (int j = 0; j < 4; ++j) {
      int c = qc * 8 + j * 32;
      bool live = (ct < qt) || (c <= g);
      float o[8] = {};
      if (live) conv_chunk(lS, g, c, wp01, wp2z, o);
      int glim = (ct == qt) ? g : 127;
      s16x8 po;
      #pragma unroll
      for (int t = 0; t < 8; ++t) {
        float e = (live && (c + t <= glim)) ? __expf(o[t]) : 0.0f;
        psum += e;
        po[t] = f2b(e);
      }
      ps[j] = po;
    }
    __syncthreads();   // conv reads done; safe to overwrite lS with P

    #pragma unroll
    for (int j = 0; j < 4; ++j)
      *(s16x8*)&lS[g * ASTR + 8 + qc * 8 + j * 32] = ps[j];
    __syncthreads();   // P ready

    // ---- PV: wave w -> out rows w*16..+15, 4 d-tiles of 16 ----
    int kl = 128;
    if (ct == qt) { kl = ((w * 16 + 16 + 31) >> 5) << 5; if (kl > 128) kl = 128; }
    for (int k0 = 0; k0 < kl; k0 += 32) {
      bf16x8 a = *(bf16x8*)&lS[(w * 16 + lr) * ASTR + 8 + k0 + lk];
      #pragma unroll
      for (int dt = 0; dt < 4; ++dt) {
        bf16x8 bv = *(const bf16x8*)&vt[(((size_t)bh * 64 + dt * 16 + lr) << 10) + n0 + k0 + lk];
        pacc[dt] = __builtin_amdgcn_mfma_f32_16x16x32_bf16(a, bv, pacc[dt], 0, 0, 0);
      }
    }
    cur ^= 1;
  }

  // ---- epilogue ----
  psum += __shfl_xor(psum, 1);
  psum += __shfl_xor(psum, 2);
  if (qc == 0) sInv[g] = 1.0f / psum;
  __syncthreads();
  #pragma unroll
  for (int dt = 0; dt < 4; ++dt)
    #pragma unroll
    for (int r = 0; r < 4; ++r) {
      int row = w * 16 + (lane >> 4) * 4 + r;
      float ov = pacc[dt][r] * sInv[row];
      O[((size_t)(b * 1024 + m0 + row) << 10) + h * 64 + dt * 16 + lr] = f2b(ov);
    }
}

// ---------------- LN + gelu over 2 split-K partials + column bias, fp32[*,2048] -> bf16 ----------------
__global__ __launch_bounds__(256) void k_ln_gelu2048(const float* __restrict__ x, const float* __restrict__ cb,
                                                     const float* __restrict__ g, const float* __restrict__ be,
                                                     short* __restrict__ out)
{
  __shared__ float red[8];
  int row = blockIdx.x, tid = threadIdx.x;
  const float* xr0 = x + (size_t)row * 2048;
  const float* xr1 = x + (size_t)(1024 + row) * 2048;
  int c0 = tid * 8;
  f32x4 a  = *(const f32x4*)&xr0[c0];
  f32x4 bb = *(const f32x4*)&xr0[c0 + 4];
  f32x4 a1 = *(const f32x4*)&xr1[c0];
  f32x4 b1 = *(const f32x4*)&xr1[c0 + 4];
  f32x4 cb0 = *(const f32x4*)&cb[c0], cb1 = *(const f32x4*)&cb[c0 + 4];
  a += a1 + cb0; bb += b1 + cb1;
  float s = 0, s2 = 0;
  #pragma unroll
  for (int t = 0; t < 4; ++t) { s += a[t] + bb[t]; s2 += a[t]*a[t] + bb[t]*bb[t]; }
  #pragma unroll
  for (int off = 32; off; off >>= 1) { s += __shfl_xor(s, off); s2 += __shfl_xor(s2, off); }
  if ((tid & 63) == 0) { red[tid >> 6] = s; red[4 + (tid >> 6)] = s2; }
  __syncthreads();
  s  = red[0] + red[1] + red[2] + red[3];
  s2 = red[4] + red[5] + red[6] + red[7];
  float mean = s * (1.0f / 2048.0f);
  float var  = s2 * (1.0f / 2048.0f) - mean * mean;
  float inv  = rsqrtf(var + 1e-5f);
  f32x4 g0 = *(const f32x4*)&g[c0],  g1 = *(const f32x4*)&g[c0 + 4];
  f32x4 e0 = *(const f32x4*)&be[c0], e1 = *(const f32x4*)&be[c0 + 4];
  s16x8 o;
  #pragma unroll
  for (int t = 0; t < 4; ++t) {
    o[t]     = f2b(gelu_f((a[t]  - mean) * inv * g0[t] + e0[t]));
    o[t + 4] = f2b(gelu_f((bb[t] - mean) * inv * g1[t] + e1[t]));
  }
  *(s16x8*)&out[(size_t)row * 2048 + c0] = o;
}

// ---------------- reduce 4 split-K partials + bias + gelu -> tbuf[1024,512] ----------------
__global__ __launch_bounds__(256) void k_red_gelu(const float* __restrict__ p, const float* __restrict__ b1,
                                                  float* __restrict__ out)
{
  int i = (blockIdx.x * 256 + threadIdx.x) * 4;
  f32x4 s = *(const f32x4*)&p[i];
  #pragma unroll
  for (int z = 1; z < 4; ++z) s += *(const f32x4*)&p[(size_t)z * 524288 + i];
  f32x4 bv = *(const f32x4*)&b1[i & 511];
  f32x4 o;
  #pragma unroll
  for (int t = 0; t < 4; ++t) o[t] = gelu_f(s[t] + bv[t]);
  *(f32x4*)&out[i] = o;
}

// ---------------- aw logits: t[1024,512] . w2[512] + b2 (one wave per row) ----------------
__global__ __launch_bounds__(256) void k_aw_logit(const float* __restrict__ t, const float* __restrict__ w2,
                                                  const float* __restrict__ b2, float* __restrict__ logit)
{
  int row = blockIdx.x * 4 + (threadIdx.x >> 6);
  int lane = threadIdx.x & 63;
  float s = 0;
  for (int c = lane; c < 512; c += 64) s += t[(size_t)row * 512 + c] * w2[c];
  #pragma unroll
  for (int off = 32; off; off >>= 1) s += __shfl_xor(s, off);
  if (lane == 0) logit[row] = s + b2[0];
}

// ---------------- softmax (redundant per block) + weighted pool: block (cchunk, b) ----------------
__global__ __launch_bounds__(256) void k_softmax_cc(const float* __restrict__ logit, const short* __restrict__ ehb,
                                                    float* __restrict__ cc)
{
  __shared__ float sw[256];
  __shared__ float red[8];
  int b = blockIdx.y, ch = blockIdx.x, tid = threadIdx.x;
  float v = logit[b * 256 + tid];
  float m = v;
  #pragma unroll
  for (int off = 32; off; off >>= 1) m = fmaxf(m, __shfl_xor(m, off));
  if ((tid & 63) == 0) red[tid >> 6] = m;
  __syncthreads();
  float M = fmaxf(fmaxf(red[0], red[1]), fmaxf(red[2], red[3]));
  float e = __expf(v - M);
  float s = e;
  #pragma unroll
  for (int off = 32; off; off >>= 1) s += __shfl_xor(s, off);
  if ((tid & 63) == 0) red[4 + (tid >> 6)] = s;
  __syncthreads();
  float invS = 1.0f / (red[4] + red[5] + red[6] + red[7]);
  sw[tid] = e * invS;
  __syncthreads();
  int c = ch * 256 + tid;
  float a = 0;
  for (int t = 0; t < 256; ++t) a += sw[t] * b2f(ehb[(((size_t)(b * 256 + t)) << 11) + c]);
  cc[(b << 11) + c] = a;
}

// ---------------- kg1 split-K partials: 128 blocks ----------------
__global__ __launch_bounds__(256) void k_kg1p(const float* __restrict__ cc, const float* __restrict__ W1,
                                              float* __restrict__ part)
{
  int d = blockIdx.x * 256 + threadIdx.x;
  int kc = blockIdx.y;
  float s0 = 0, s1 = 0, s2 = 0, s3 = 0;
  for (int k = kc * 64; k < kc * 64 + 64; ++k) {
    float w = W1[(size_t)k * 1024 + d];
    s0 += cc[k] * w; s1 += cc[2048 + k] * w; s2 += cc[4096 + k] * w; s3 += cc[6144 + k] * w;
  }
  part[(size_t)(kc * 4 + 0) * 1024 + d] = s0;
  part[(size_t)(kc * 4 + 1) * 1024 + d] = s1;
  part[(size_t)(kc * 4 + 2) * 1024 + d] = s2;
  part[(size_t)(kc * 4 + 3) * 1024 + d] = s3;
}

// ---------------- kg mid: reduce partials + bias, LN, gelu -> kgh bf16 ----------------
__global__ __launch_bounds__(256) void k_kg_mid(const float* __restrict__ part, const float* __restrict__ b1,
                                                const float* __restrict__ g, const float* __restrict__ be,
                                                short* __restrict__ kgh)
{
  __shared__ float red[8];
  int b = blockIdx.x, tid = threadIdx.x;
  float v[4]; float s = 0, s2 = 0;
  #pragma unroll
  for (int qi = 0; qi < 4; ++qi) {
    int d = tid + qi * 256;
    float acc = b1[d];
    for (int kc = 0; kc < 32; ++kc) acc += part[(size_t)(kc * 4 + b) * 1024 + d];
    v[qi] = acc; s += acc; s2 += acc * acc;
  }
  #pragma unroll
  for (int off = 32; off; off >>= 1) { s += __shfl_xor(s, off); s2 += __shfl_xor(s2, off); }
  if ((tid & 63) == 0) { red[tid >> 6] = s; red[4 + (tid >> 6)] = s2; }
  __syncthreads();
  s  = red[0] + red[1] + red[2] + red[3];
  s2 = red[4] + red[5] + red[6] + red[7];
  float mean = s * (1.0f / 1024.0f);
  float var  = s2 * (1.0f / 1024.0f) - mean * mean;
  float inv  = rsqrtf(var + 1e-5f);
  #pragma unroll
  for (int qi = 0; qi < 4; ++qi) {
    int d = tid + qi * 256;
    kgh[b * 1024 + d] = f2b(gelu_f((v[qi] - mean) * inv * g[d] + be[d]));
  }
}

// ---------------- kp + softmax9: one wave per (h,b) ----------------
__global__ __launch_bounds__(64) void k_kp2(const short* __restrict__ kgh, const float* __restrict__ W2,
                                            const float* __restrict__ b2, float* __restrict__ kern)
{
  int h = blockIdx.x, b = blockIdx.y, lane = threadIdx.x;
  float kg[16];
  #pragma unroll
  for (int m = 0; m < 16; ++m) kg[m] = b2f(kgh[b * 1024 + lane + m * 64]);
  float dj[9];
  #pragma unroll
  for (int j = 0; j < 9; ++j) {
    float s = 0;
    #pragma unroll
    for (int m = 0; m < 16; ++m) s += kg[m] * W2[(size_t)(lane + m * 64) * 144 + h * 9 + j];
    #pragma unroll
    for (int off = 32; off; off >>= 1) s += __shfl_xor(s, off);
    dj[j] = s + b2[h * 9 + j];
  }
  if (lane == 0) {
    float m = dj[0];
    #pragma unroll
    for (int j = 1; j < 9; ++j) m = fmaxf(m, dj[j]);
    float e[9], s = 0;
    #pragma unroll
    for (int j = 0; j < 9; ++j) { e[j] = __expf(dj[j] - m); s += e[j]; }
    float inv = 1.0f / s;
    #pragma unroll
    for (int j = 0; j < 9; ++j) kern[(b * 16 + h) * 9 + j] = e[j] * inv;
  }
}

__global__ void k_fail(float* out){ out[threadIdx.x] = 1.0e9f; }

extern "C" void kernel_launch(void* const* d_in, const int* in_sizes, int n_in,
                              void* d_out, int out_size, void* d_ws, size_t ws_size,
                              hipStream_t stream) {
  (void)in_sizes; (void)n_in; (void)out_size;
  const float* x       = (const float*)d_in[0];
  const float* hist    = (const float*)d_in[1];
  const float* Wq      = (const float*)d_in[2];
  const float* Wk      = (const float*)d_in[3];
  const float* Wv      = (const float*)d_in[4];
  const float* hist_W  = (const float*)d_in[5];
  const float* hist_b  = (const float*)d_in[6];
  const float* hln_g   = (const float*)d_in[7];
  const float* hln_b   = (const float*)d_in[8];
  const float* ctx_W1  = (const float*)d_in[9];
  const float* ctx_b1  = (const float*)d_in[10];
  const float* ctx_W2  = (const float*)d_in[11];
  const float* ctx_b2  = (const float*)d_in[12];
  const float* kg_W1   = (const float*)d_in[13];
  const float* kg_b1   = (const float*)d_in[14];
  const float* kln_g   = (const float*)d_in[15];
  const float* kln_b   = (const float*)d_in[16];
  const float* kg_W2   = (const float*)d_in[17];
  const float* kg_b2   = (const float*)d_in[18];
  const float* proj_W  = (const float*)d_in[19];
  const float* proj_b  = (const float*)d_in[20];
  float* outp = (float*)d_out;

  char* wsb = (char*)d_ws;
  size_t off = 0;
  auto nxt = [&](size_t bytes) { void* p = wsb + off; off += (bytes + 255) & ~(size_t)255; return p; };

  short* xb     = (short*)nxt((size_t)4096*1024*2);
  short* wqkvt  = (short*)nxt((size_t)3*1024*1024*2);
  short* qb     = (short*)nxt((size_t)64*1026*64*2);   // padded
  short* kb     = (short*)nxt((size_t)64*1026*64*2);   // padded
  short* vtb    = (short*)nxt((size_t)64*64*1024*2);
  short* Ob     = (short*)nxt((size_t)4096*1024*2);
  short* histb  = (short*)nxt((size_t)1024*1024*2);
  short* whtb   = (short*)nxt((size_t)2048*1024*2);
  float* ehpreP = (float*)nxt((size_t)2*1024*2048*4);  // 2 split-K partials
  short* ehb    = (short*)nxt((size_t)1024*2048*2);
  short* wc1tb  = (short*)nxt((size_t)512*2048*2);
  float* ctxP   = (float*)nxt((size_t)4*1024*512*4);   // 4 split-K partials
  float* tbuf   = (float*)nxt((size_t)1024*512*4);
  float* logit  = (float*)nxt((size_t)1024*4);
  float* ccb    = (float*)nxt((size_t)4*2048*4);
  float* kgpart = (float*)nxt((size_t)128*1024*4);
  short* kghb   = (short*)nxt((size_t)4*1024*2);
  float* kernb  = (float*)nxt((size_t)64*9*4);
  short* wptb   = (short*)nxt((size_t)1024*1024*2);

  if (ws_size < off) { k_fail<<<1, 64, 0, stream>>>(outp); return; }

  // casts + pad zeroing + weight transposes
  k_cast_all<<<2568, 256, 0, stream>>>(x, hist, xb, histb, qb, kb);
  k_tcast_all<<<7168, 256, 0, stream>>>(Wq, Wk, Wv, proj_W, hist_W, ctx_W1, wqkvt, wptb, whtb, wc1tb);

  // context path (split-K on the two skinny GEMMs)
  k_gemm_f32out<<<dim3(16, 8, 2), 256, 0, stream>>>(histb, whtb, ehpreP, nullptr, 2048, 1024, 512, 2);
  k_ln_gelu2048<<<1024, 256, 0, stream>>>(ehpreP, hist_b, hln_g, hln_b, ehb);
  k_gemm_f32out<<<dim3(4, 8, 4), 256, 0, stream>>>(ehb, wc1tb, ctxP, nullptr, 512, 2048, 512, 2);
  k_red_gelu<<<512, 256, 0, stream>>>(ctxP, ctx_b1, tbuf);
  k_aw_logit<<<256, 256, 0, stream>>>(tbuf, ctx_W2, ctx_b2, logit);
  k_softmax_cc<<<dim3(8, 4), 256, 0, stream>>>(logit, ehb, ccb);
  k_kg1p<<<dim3(4, 32), 256, 0, stream>>>(ccb, kg_W1, kgpart);
  k_kg_mid<<<4, 256, 0, stream>>>(kgpart, kg_b1, kln_g, kln_b, kghb);
  k_kp2<<<dim3(16, 4), 64, 0, stream>>>(kghb, kg_W2, kg_b2, kernb);

  // attention path
  k_gemm_qkv<<<dim3(24, 32), 256, 0, stream>>>(xb, wqkvt, qb, kb, vtb);
  k_attn<<<dim3(8, 64), 512, 0, stream>>>(qb, kb, vtb, kernb, Ob);
  k_gemm_f32out<<<dim3(8, 32, 1), 256, 0, stream>>>(Ob, wptb, outp, proj_b, 1024, 1024, 1024, 0);
}

// Round 9
// 263.064 us; speedup vs baseline: 1.3312x; 1.0678x over previous
//
#include <hip/hip_runtime.h>
#include <hip/hip_bf16.h>
#include <math.h>

#define DEV static __device__ __forceinline__

typedef __attribute__((ext_vector_type(4))) float f32x4;
typedef __attribute__((ext_vector_type(8))) __bf16 bf16x8;
typedef __attribute__((ext_vector_type(8))) short s16x8;
typedef __attribute__((ext_vector_type(2))) _Float16 h16x2;

DEV float b2f(short v){ unsigned u = ((unsigned)(unsigned short)v) << 16; float f; __builtin_memcpy(&f, &u, 4); return f; }
DEV short f2b(float f){ unsigned u; __builtin_memcpy(&u, &f, 4); unsigned r = (u + 0x7fffu + ((u >> 16) & 1u)) >> 16; return (short)r; }
DEV short f2h(float f){ _Float16 h = (_Float16)f; short s; __builtin_memcpy(&s, &h, 2); return s; }
DEV h16x2 u2h2(unsigned u){ h16x2 h; __builtin_memcpy(&h, &u, 4); return h; }
DEV float gelu_f(float v){ return 0.5f * v * (1.0f + erff(v * 0.70710678118654752f)); }

DEV void gload16(const void* g, void* l) {
  __builtin_amdgcn_global_load_lds((const __attribute__((address_space(1))) unsigned int*)g,
                                   (__attribute__((address_space(3))) unsigned int*)l, 16, 0, 0);
}

// XCD-bijective swizzle over a 2D grid (requires nx*ny % 8 == 0)
DEV void xy_swz(int& bx, int& by, int nx, int ny) {
  int lin = by * nx + bx;
  int q = (nx * ny) >> 3;
  int l2 = (lin & 7) * q + (lin >> 3);
  bx = l2 % nx; by = l2 / nx;
}

// ---------------- fused cast fp32 -> bf16 for x and hist + q/k pad-row zeroing ----------------
__global__ __launch_bounds__(256) void k_cast_all(const float* __restrict__ x, const float* __restrict__ hist,
                                                  short* __restrict__ xb, short* __restrict__ histb,
                                                  short* __restrict__ q, short* __restrict__ kk){
  int bid = blockIdx.x;
  if (bid >= 2560) {              // zero pad rows 0 and 1025 of padded q/k
    int idx = (bid - 2560) * 256 + threadIdx.x;   // 0..2047
    int bh = idx >> 5, c = idx & 31;
    int which = c >> 3, chunk = c & 7;
    short* base = (which < 2) ? q : kk;
    size_t off = (size_t)bh * 1026 * 64 + ((which & 1) ? (size_t)1025 * 64 : 0) + chunk * 8;
    s16x8 zz = {};
    *(s16x8*)&base[off] = zz;
    return;
  }
  const float* in; short* out; int i;
  if (bid < 2048) { in = x; out = xb; i = (bid * 256 + threadIdx.x) * 8; }
  else            { in = hist; out = histb; i = ((bid - 2048) * 256 + threadIdx.x) * 8; }
  f32x4 a = *(const f32x4*)&in[i];
  f32x4 b = *(const f32x4*)&in[i + 4];
  s16x8 o;
  o[0]=f2b(a[0]); o[1]=f2b(a[1]); o[2]=f2b(a[2]); o[3]=f2b(a[3]);
  o[4]=f2b(b[0]); o[5]=f2b(b[1]); o[6]=f2b(b[2]); o[7]=f2b(b[3]);
  *(s16x8*)&out[i] = o;
}

// ---------------- all weight transpose-casts in one launch ----------------
DEV void tcast_tile(const float* __restrict__ W, short* __restrict__ Wt, int K, int N, int tx, int ty){
  __shared__ float tile[32][33];
  int nb = tx * 32, kb = ty * 32;
  int tid = threadIdx.x;
  int c = tid & 31, r0 = tid >> 5;
  #pragma unroll
  for (int r = r0; r < 32; r += 8) tile[r][c] = W[(size_t)(kb + r) * N + nb + c];
  __syncthreads();
  #pragma unroll
  for (int r = r0; r < 32; r += 8) Wt[(size_t)(nb + r) * K + kb + c] = f2b(tile[c][r]);
}
__global__ __launch_bounds__(256) void k_tcast_all(const float* __restrict__ Wq, const float* __restrict__ Wk,
                                                   const float* __restrict__ Wv, const float* __restrict__ projW,
                                                   const float* __restrict__ histW, const float* __restrict__ ctxW1,
                                                   short* __restrict__ wqkvt, short* __restrict__ wptb,
                                                   short* __restrict__ whtb, short* __restrict__ wc1tb){
  int bid = blockIdx.x;
  const float* W; short* Wt; int K, N, tx, ty;
  if (bid < 4096) {
    int seg = bid >> 10, t = bid & 1023;
    tx = t & 31; ty = t >> 5; K = 1024; N = 1024;
    if      (seg == 0) { W = Wq;    Wt = wqkvt; }
    else if (seg == 1) { W = Wk;    Wt = wqkvt + 1024*1024; }
    else if (seg == 2) { W = Wv;    Wt = wqkvt + 2*1024*1024; }
    else               { W = projW; Wt = wptb; }
  } else if (bid < 6144) {
    int t = bid - 4096; tx = t & 63; ty = t >> 6; K = 1024; N = 2048; W = histW; Wt = whtb;
  } else {
    int t = bid - 6144; tx = t & 15; ty = t >> 4; K = 2048; N = 512; W = ctxW1; Wt = wc1tb;
  }
  tcast_tile(W, Wt, K, N, tx, ty);
}

// ---------------- GEMM core: per-wave acc = A[m0:m0+128, kt..kt+Ks] * Bt[n0:n0+128, ...]^T ----------------
DEV void gemm_core(const short* __restrict__ A, const short* __restrict__ Bt,
                   int Ks, int lda, int ldb, int m0, int n0,
                   short* lA, short* lB, f32x4 acc[4][4])
{
  const int tid = threadIdx.x;
  const int lane = tid & 63;
  const int w = tid >> 6;
  const int wr = (w >> 1) * 64, wc = (w & 1) * 64;
  const int lr = lane & 15, lk = (lane >> 4) * 8;
  for (int kt = 0; kt < Ks; kt += 64) {
    __syncthreads();
    #pragma unroll
    for (int i = 0; i < 4; ++i) {
      int off = i * 2048 + tid * 8;
      int r = off >> 6, c = off & 63;
      gload16(&A[(size_t)(m0 + r) * lda + kt + c], &lA[off]);
      gload16(&Bt[(size_t)(n0 + r) * ldb + kt + c], &lB[off]);
    }
    __syncthreads();
    #pragma unroll
    for (int kk = 0; kk < 64; kk += 32) {
      bf16x8 af[4], bfr[4];
      #pragma unroll
      for (int mi = 0; mi < 4; ++mi) af[mi] = *(bf16x8*)&lA[(wr + mi*16 + lr)*64 + kk + lk];
      #pragma unroll
      for (int ni = 0; ni < 4; ++ni) bfr[ni] = *(bf16x8*)&lB[(wc + ni*16 + lr)*64 + kk + lk];
      #pragma unroll
      for (int mi = 0; mi < 4; ++mi)
        #pragma unroll
        for (int ni = 0; ni < 4; ++ni)
          acc[mi][ni] = __builtin_amdgcn_mfma_f32_16x16x32_bf16(af[mi], bfr[ni], acc[mi][ni], 0, 0, 0);
    }
  }
}

// ---------------- GEMM, fp32 out; mode 0: +bias, 1: +bias+gelu, 2: raw split-K partial ----------------
__global__ __launch_bounds__(256) void k_gemm_f32out(const short* __restrict__ A, const short* __restrict__ Bt,
                                                     float* __restrict__ Cout, const float* __restrict__ bias,
                                                     int N, int lda, int Ks, int mode)
{
  __shared__ __align__(16) short lds[2 * 128 * 64];
  f32x4 acc[4][4] = {};
  int bx = blockIdx.x, by = blockIdx.y;
  xy_swz(bx, by, gridDim.x, gridDim.y);
  int m0 = by * 128, n0 = bx * 128;
  int koff = blockIdx.z * Ks;
  gemm_core(A + koff, Bt + koff, Ks, lda, lda, m0, n0, lds, lds + 128*64, acc);
  Cout += (size_t)blockIdx.z * gridDim.y * 128 * N;
  int lane = threadIdx.x & 63, w = threadIdx.x >> 6;
  int wr = (w>>1)*64, wc = (w&1)*64, lr4 = (lane>>4)*4, lc = lane & 15;
  #pragma unroll
  for (int mi = 0; mi < 4; ++mi)
    #pragma unroll
    for (int ni = 0; ni < 4; ++ni)
      #pragma unroll
      for (int r = 0; r < 4; ++r) {
        int row = m0 + wr + mi*16 + lr4 + r;
        int col = n0 + wc + ni*16 + lc;
        float v = acc[mi][ni][r];
        if (mode != 2) v += bias[col];
        if (mode == 1) v = gelu_f(v);
        Cout[(size_t)row * N + col] = v;
      }
}

// ---------------- fused QKV GEMM: x[4096,1024] @ Wqkv^T, heads epilogue ----------------
__global__ __launch_bounds__(256) void k_gemm_qkv(const short* __restrict__ xb, const short* __restrict__ wqkvt,
                                                  short* __restrict__ q, short* __restrict__ kk, short* __restrict__ vt)
{
  __shared__ __align__(16) short lds[128 * 136];
  f32x4 acc[4][4] = {};
  int bx = blockIdx.x, by = blockIdx.y;
  xy_swz(bx, by, gridDim.x, gridDim.y);
  int m0 = by * 128, n0 = bx * 128;
  gemm_core(xb, wqkvt, 1024, 1024, 1024, m0, n0, lds, lds + 128*64, acc);
  int tid = threadIdx.x, lane = tid & 63, w = tid >> 6;
  int wr = (w>>1)*64, wc = (w&1)*64, lr4 = (lane>>4)*4, lc = lane & 15;
  int bb = m0 >> 10, tm0 = m0 & 1023;
  int s = n0 >> 10, dn0 = n0 & 1023;
  __syncthreads();
  if (s < 2) {
    short* dst = (s == 0) ? q : kk;
    #pragma unroll
    for (int mi = 0; mi < 4; ++mi)
      #pragma unroll
      for (int ni = 0; ni < 4; ++ni)
        #pragma unroll
        for (int r = 0; r < 4; ++r)
          lds[(wr + mi*16 + lr4 + r) * 136 + wc + ni*16 + lc] = f2b(acc[mi][ni][r]);
    __syncthreads();
    #pragma unroll
    for (int it = 0; it < 8; ++it) {
      int idx = it * 256 + tid;
      int row = idx >> 4, ch = (idx & 15) * 8;
      int dfull = dn0 + ch;
      *(s16x8*)&dst[((size_t)(bb*16 + (dfull >> 6)) * 1026 + 1 + tm0 + row) * 64 + (dfull & 63)]
          = *(s16x8*)&lds[row * 136 + ch];
    }
  } else {
    #pragma unroll
    for (int mi = 0; mi < 4; ++mi)
      #pragma unroll
      for (int ni = 0; ni < 4; ++ni)
        #pragma unroll
        for (int r = 0; r < 4; ++r)
          lds[(wc + ni*16 + lc) * 136 + wr + mi*16 + lr4 + r] = f2b(acc[mi][ni][r]);
    __syncthreads();
    #pragma unroll
    for (int it = 0; it < 8; ++it) {
      int idx = it * 256 + tid;
      int nl = idx >> 4, mc = (idx & 15) * 8;
      int dfull = dn0 + nl;
      *(s16x8*)&vt[(((size_t)(bb*16 + (dfull >> 6)) * 64 + (dfull & 63)) << 10) + tm0 + mc]
          = *(s16x8*)&lds[nl * 136 + mc];
    }
  }
}

// ---------------- fused flash attention: QK^T + conv3x3 + softmax + PV ----------------
constexpr int ASTR = 148;   // lS col stride (shorts); 296B rows -> 16-row bank period (2-way-free)

// conv over one 8-col chunk; reads lS rows g..g+2, col idx 8+c-1 .. 8+c+8
DEV void conv_chunk(const short* sS, int g, int c,
                    const h16x2 wp01[3], const h16x2 wp2z[3], float o[8]) {
  #pragma unroll
  for (int dr = 0; dr < 3; ++dr) {
    int base = (g + dr) * ASTR + 8 + c;
    const unsigned* W = (const unsigned*)&sS[base];
    unsigned U0 = W[0], U1 = W[1], U2 = W[2], U3 = W[3];
    unsigned hm1 = (unsigned short)sS[base - 1];
    unsigned hp8 = (unsigned short)sS[base + 8];
    unsigned P0 = hm1 | (U0 << 16);
    unsigned P2 = (U0 >> 16) | (U1 << 16);
    unsigned P4 = (U1 >> 16) | (U2 << 16);
    unsigned P6 = (U2 >> 16) | (U3 << 16);
    unsigned P8 = (U3 >> 16) | (hp8 << 16);
    unsigned P9 = hp8;
    unsigned pr[10] = {P0, U0, P2, U1, P4, U2, P6, U3, P8, P9};
    h16x2 a = wp01[dr], bz = wp2z[dr];
    #pragma unroll
    for (int t = 0; t < 8; ++t) {
      o[t] = __builtin_amdgcn_fdot2(a,  u2h2(pr[t]),     o[t], false);
      o[t] = __builtin_amdgcn_fdot2(bz, u2h2(pr[t + 2]), o[t], false);
    }
  }
}

__global__ __launch_bounds__(512, 4) void k_attn(const short* __restrict__ q, const short* __restrict__ kkg,
                                                 const short* __restrict__ vt, const float* __restrict__ kern,
                                                 short* __restrict__ O)
{
  // lK: chunk-swizzled (chunk c holds global chunk c ^ (row&7)); linear dest for global_load_lds.
  __shared__ __align__(16) short lK[2][144 * 64];
  __shared__ __align__(16) short lS[130 * ASTR];   // f16 S rows (global m0-1 .. m0+128)

  int bh = blockIdx.y, b = bh >> 4, h = bh & 15;
  int qt = (bh >= 32) ? 7 - blockIdx.x : blockIdx.x;   // pair heavy+light tiles
  int m0 = qt * 128;
  int tid = threadIdx.x;
  int w = tid >> 6, lane = tid & 63;
  int lr = lane & 15, hi = lane >> 4;
  int lk = hi * 8;

  const short* qp = q   + (size_t)bh * 1026 * 64;
  const short* kp = kkg + (size_t)bh * 1026 * 64;

  h16x2 wp01[3], wp2z[3];
  #pragma unroll
  for (int a = 0; a < 3; ++a) {
    wp01[a][0] = (_Float16)kern[bh * 9 + a * 3 + 0];
    wp01[a][1] = (_Float16)kern[bh * 9 + a * 3 + 1];
    wp2z[a][0] = (_Float16)kern[bh * 9 + a * 3 + 2];
    wp2z[a][1] = (_Float16)0.0f;
  }

  // main Q fragment: wave w covers global rows m0-1+16w .. m0+14+16w (padded idx m0+16w+lr)
  bf16x8 qf0, qf1;
  {
    const short* qrow = &qp[(size_t)(m0 + w * 16 + lr) * 64];
    qf0 = *(const bf16x8*)&qrow[lk];
    qf1 = *(const bf16x8*)&qrow[32 + lk];
  }
  // extra tile: global rows m0+113 .. m0+128 (padded m0+114+lr); only rows 14,15 are written
  bf16x8 qe0, qe1;
  {
    const short* qrow = &qp[(size_t)(m0 + 114 + lr) * 64];
    qe0 = *(const bf16x8*)&qrow[lk];
    qe1 = *(const bf16x8*)&qrow[32 + lk];
  }

  s16x8 zz = {};
  // zero lK rows 130..143 (both buffers; persists — nt=8 reads them)
  for (int t = tid; t < 14 * 8; t += 512) {
    *(s16x8*)&lK[0][(130 * 8 + t) * 8] = zz;
    *(s16x8*)&lK[1][(130 * 8 + t) * 8] = zz;
  }
  // stage K(ct=0): dest linear chunk t (16B), source chunk (t&7)^(row&7)
  for (int t = tid; t < 130 * 8; t += 512) {
    int r = t >> 3;
    gload16(&kp[((size_t)r) * 64 + (((t & 7) ^ (r & 7)) << 3)], &lK[0][t * 8]);
  }

  f32x4 pacc[4] = {};
  float psum = 0.0f;
  int cur = 0;

  for (int ct = 0; ct <= qt; ++ct) {
    int n0 = ct * 128;
    __syncthreads();   // K(ct) landed (vmcnt drained at barrier); all prev conv reads of lS done
    if (ct < qt) {     // prefetch K(ct+1) — overlaps QK^T phase
      int n1 = n0 + 128;
      for (int t = tid; t < 130 * 8; t += 512) {
        int r = t >> 3;
        gload16(&kp[((size_t)(n1 + r)) * 64 + (((t & 7) ^ (r & 7)) << 3)], &lK[cur ^ 1][t * 8]);
      }
    }
    const short* lKc = lK[cur];

    // ---- QK^T main: wave w -> lS rows 16w..16w+15 ----
    int ntmax = (ct == qt) ? (w + 2) : 9;
    for (int nt = 0; nt < ntmax; ++nt) {
      int krow = nt * 16 + lr;
      int sw = (krow & 7) << 3;
      bf16x8 bk0 = *(bf16x8*)&lKc[krow * 64 + (( hi      << 3) ^ sw)];
      bf16x8 bk1 = *(bf16x8*)&lKc[krow * 64 + (((hi + 4) << 3) ^ sw)];
      f32x4 acc = {};
      acc = __builtin_amdgcn_mfma_f32_16x16x32_bf16(qf0, bk0, acc, 0, 0, 0);
      acc = __builtin_amdgcn_mfma_f32_16x16x32_bf16(qf1, bk1, acc, 0, 0, 0);
      int cloc = krow - 1;
      if (cloc <= 128) {
        #pragma unroll
        for (int r = 0; r < 4; ++r) {
          int rl = w * 16 + hi * 4 + r;            // lS row; global q row = m0-1+rl
          float v = acc[r] * 0.125f;
          if (n0 + cloc > m0 - 1 + rl) v = 0.0f;
          lS[rl * ASTR + 8 + cloc] = f2h(v);
        }
      }
    }
    // ---- QK^T extra tile (rows m0+127,m0+128 -> lS rows 128,129); wave w does nt=w, wave 0 also nt=8 ----
    #pragma unroll
    for (int e = 0; e < 2; ++e) {
      if (e == 1 && w != 0) break;
      int nt = (e == 0) ? w : 8;
      int krow = nt * 16 + lr;
      int sw = (krow & 7) << 3;
      bf16x8 bk0 = *(bf16x8*)&lKc[krow * 64 + (( hi      << 3) ^ sw)];
      bf16x8 bk1 = *(bf16x8*)&lKc[krow * 64 + (((hi + 4) << 3) ^ sw)];
      f32x4 acc = {};
      acc = __builtin_amdgcn_mfma_f32_16x16x32_bf16(qe0, bk0, acc, 0, 0, 0);
      acc = __builtin_amdgcn_mfma_f32_16x16x32_bf16(qe1, bk1, acc, 0, 0, 0);
      int cloc = krow - 1;
      if (hi == 3 && cloc <= 128) {
        #pragma unroll
        for (int r = 2; r < 4; ++r) {
          int rowt = 12 + r;                        // 14,15 -> lS rows 128,129
          float v = acc[r] * 0.125f;
          if (n0 + cloc > m0 + 113 + rowt) v = 0.0f;
          lS[(114 + rowt) * ASTR + 8 + cloc] = f2h(v);
        }
      }
    }
    __syncthreads();   // S tile complete

    // ---- conv + exp: lane -> output row g = 16w+lr, chunks c = hi*8 + 32j (== PV A-fragment layout) ----
    int g = w * 16 + lr;
    s16x8 pa[4];
    #pragma unroll
    for (int j = 0; j < 4; ++j) {
      int c = hi * 8 + 32 * j;
      bool live = (ct < qt) || (c <= g);
      float o[8] = {};
      if (live) conv_chunk(lS, g, c, wp01, wp2z, o);
      int glim = (ct == qt) ? g : 127;
      s16x8 po;
      #pragma unroll
      for (int t = 0; t < 8; ++t) {
        float e = (live && (c + t <= glim)) ? __expf(o[t]) : 0.0f;
        psum += e;
        po[t] = f2b(e);
      }
      pa[j] = po;
    }

    // ---- PV straight from registers: pa[j] is the A-fragment for k-slice 32j ----
    int kl = 128;
    if (ct == qt) { kl = ((w * 16 + 16 + 31) >> 5) << 5; if (kl > 128) kl = 128; }
    #pragma unroll
    for (int j = 0; j < 4; ++j) {
      if (j * 32 < kl) {
        bf16x8 af;
        __builtin_memcpy(&af, &pa[j], 16);
        #pragma unroll
        for (int dt = 0; dt < 4; ++dt) {
          bf16x8 bv = *(const bf16x8*)&vt[(((size_t)bh * 64 + dt * 16 + lr) << 10) + n0 + j * 32 + lk];
          pacc[dt] = __builtin_amdgcn_mfma_f32_16x16x32_bf16(af, bv, pacc[dt], 0, 0, 0);
        }
      }
    }
    cur ^= 1;
  }

  // ---- epilogue: row sums via shuffles (lanes {lr,lr+16,lr+32,lr+48} share row 16w+lr) ----
  psum += __shfl_xor(psum, 16);
  psum += __shfl_xor(psum, 32);
  #pragma unroll
  for (int r = 0; r < 4; ++r) {
    float sInvR = 1.0f / __shfl(psum, hi * 4 + r, 64);
    int row = w * 16 + hi * 4 + r;
    #pragma unroll
    for (int dt = 0; dt < 4; ++dt) {
      float ov = pacc[dt][r] * sInvR;
      O[((size_t)(b * 1024 + m0 + row) << 10) + h * 64 + dt * 16 + lr] = f2b(ov);
    }
  }
}

// ---------------- LN + gelu over 2 split-K partials + column bias, fp32[*,2048] -> bf16 ----------------
__global__ __launch_bounds__(256) void k_ln_gelu2048(const float* __restrict__ x, const float* __restrict__ cb,
                                                     const float* __restrict__ g, const float* __restrict__ be,
                                                     short* __restrict__ out)
{
  __shared__ float red[8];
  int row = blockIdx.x, tid = threadIdx.x;
  const float* xr0 = x + (size_t)row * 2048;
  const float* xr1 = x + (size_t)(1024 + row) * 2048;
  int c0 = tid * 8;
  f32x4 a  = *(const f32x4*)&xr0[c0];
  f32x4 bb = *(const f32x4*)&xr0[c0 + 4];
  f32x4 a1 = *(const f32x4*)&xr1[c0];
  f32x4 b1 = *(const f32x4*)&xr1[c0 + 4];
  f32x4 cb0 = *(const f32x4*)&cb[c0], cb1 = *(const f32x4*)&cb[c0 + 4];
  a += a1 + cb0; bb += b1 + cb1;
  float s = 0, s2 = 0;
  #pragma unroll
  for (int t = 0; t < 4; ++t) { s += a[t] + bb[t]; s2 += a[t]*a[t] + bb[t]*bb[t]; }
  #pragma unroll
  for (int off = 32; off; off >>= 1) { s += __shfl_xor(s, off); s2 += __shfl_xor(s2, off); }
  if ((tid & 63) == 0) { red[tid >> 6] = s; red[4 + (tid >> 6)] = s2; }
  __syncthreads();
  s  = red[0] + red[1] + red[2] + red[3];
  s2 = red[4] + red[5] + red[6] + red[7];
  float mean = s * (1.0f / 2048.0f);
  float var  = s2 * (1.0f / 2048.0f) - mean * mean;
  float inv  = rsqrtf(var + 1e-5f);
  f32x4 g0 = *(const f32x4*)&g[c0],  g1 = *(const f32x4*)&g[c0 + 4];
  f32x4 e0 = *(const f32x4*)&be[c0], e1 = *(const f32x4*)&be[c0 + 4];
  s16x8 o;
  #pragma unroll
  for (int t = 0; t < 4; ++t) {
    o[t]     = f2b(gelu_f((a[t]  - mean) * inv * g0[t] + e0[t]));
    o[t + 4] = f2b(gelu_f((bb[t] - mean) * inv * g1[t] + e1[t]));
  }
  *(s16x8*)&out[(size_t)row * 2048 + c0] = o;
}

// ---------------- reduce 4 split-K partials + bias + gelu -> tbuf[1024,512] ----------------
__global__ __launch_bounds__(256) void k_red_gelu(const float* __restrict__ p, const float* __restrict__ b1,
                                                  float* __restrict__ out)
{
  int i = (blockIdx.x * 256 + threadIdx.x) * 4;
  f32x4 s = *(const f32x4*)&p[i];
  #pragma unroll
  for (int z = 1; z < 4; ++z) s += *(const f32x4*)&p[(size_t)z * 524288 + i];
  f32x4 bv = *(const f32x4*)&b1[i & 511];
  f32x4 o;
  #pragma unroll
  for (int t = 0; t < 4; ++t) o[t] = gelu_f(s[t] + bv[t]);
  *(f32x4*)&out[i] = o;
}

// ---------------- aw logits: t[1024,512] . w2[512] + b2 (one wave per row) ----------------
__global__ __launch_bounds__(256) void k_aw_logit(const float* __restrict__ t, const float* __restrict__ w2,
                                                  const float* __restrict__ b2, float* __restrict__ logit)
{
  int row = blockIdx.x * 4 + (threadIdx.x >> 6);
  int lane = threadIdx.x & 63;
  float s = 0;
  for (int c = lane; c < 512; c += 64) s += t[(size_t)row * 512 + c] * w2[c];
  #pragma unroll
  for (int off = 32; off; off >>= 1) s += __shfl_xor(s, off);
  if (lane == 0) logit[row] = s + b2[0];
}

// ---------------- softmax (redundant per block) + weighted pool: block (cchunk, b) ----------------
__global__ __launch_bounds__(256) void k_softmax_cc(const float* __restrict__ logit, const short* __restrict__ ehb,
                                                    float* __restrict__ cc)
{
  __shared__ float sw[256];
  __shared__ float red[8];
  int b = blockIdx.y, ch = blockIdx.x, tid = threadIdx.x;
  float v = logit[b * 256 + tid];
  float m = v;
  #pragma unroll
  for (int off = 32; off; off >>= 1) m = fmaxf(m, __shfl_xor(m, off));
  if ((tid & 63) == 0) red[tid >> 6] = m;
  __syncthreads();
  float M = fmaxf(fmaxf(red[0], red[1]), fmaxf(red[2], red[3]));
  float e = __expf(v - M);
  float s = e;
  #pragma unroll
  for (int off = 32; off; off >>= 1) s += __shfl_xor(s, off);
  if ((tid & 63) == 0) red[4 + (tid >> 6)] = s;
  __syncthreads();
  float invS = 1.0f / (red[4] + red[5] + red[6] + red[7]);
  sw[tid] = e * invS;
  __syncthreads();
  int c = ch * 256 + tid;
  float a = 0;
  for (int t = 0; t < 256; ++t) a += sw[t] * b2f(ehb[(((size_t)(b * 256 + t)) << 11) + c]);
  cc[(b << 11) + c] = a;
}

// ---------------- kg1 split-K partials: 128 blocks ----------------
__global__ __launch_bounds__(256) void k_kg1p(const float* __restrict__ cc, const float* __restrict__ W1,
                                              float* __restrict__ part)
{
  int d = blockIdx.x * 256 + threadIdx.x;
  int kc = blockIdx.y;
  float s0 = 0, s1 = 0, s2 = 0, s3 = 0;
  for (int k = kc * 64; k < kc * 64 + 64; ++k) {
    float w = W1[(size_t)k * 1024 + d];
    s0 += cc[k] * w; s1 += cc[2048 + k] * w; s2 += cc[4096 + k] * w; s3 += cc[6144 + k] * w;
  }
  part[(size_t)(kc * 4 + 0) * 1024 + d] = s0;
  part[(size_t)(kc * 4 + 1) * 1024 + d] = s1;
  part[(size_t)(kc * 4 + 2) * 1024 + d] = s2;
  part[(size_t)(kc * 4 + 3) * 1024 + d] = s3;
}

// ---------------- kg mid: reduce partials + bias, LN, gelu -> kgh bf16 ----------------
__global__ __launch_bounds__(256) void k_kg_mid(const float* __restrict__ part, const float* __restrict__ b1,
                                                const float* __restrict__ g, const float* __restrict__ be,
                                                short* __restrict__ kgh)
{
  __shared__ float red[8];
  int b = blockIdx.x, tid = threadIdx.x;
  float v[4]; float s = 0, s2 = 0;
  #pragma unroll
  for (int qi = 0; qi < 4; ++qi) {
    int d = tid + qi * 256;
    float acc = b1[d];
    for (int kc = 0; kc < 32; ++kc) acc += part[(size_t)(kc * 4 + b) * 1024 + d];
    v[qi] = acc; s += acc; s2 += acc * acc;
  }
  #pragma unroll
  for (int off = 32; off; off >>= 1) { s += __shfl_xor(s, off); s2 += __shfl_xor(s2, off); }
  if ((tid & 63) == 0) { red[tid >> 6] = s; red[4 + (tid >> 6)] = s2; }
  __syncthreads();
  s  = red[0] + red[1] + red[2] + red[3];
  s2 = red[4] + red[5] + red[6] + red[7];
  float mean = s * (1.0f / 1024.0f);
  float var  = s2 * (1.0f / 1024.0f) - mean * mean;
  float inv  = rsqrtf(var + 1e-5f);
  #pragma unroll
  for (int qi = 0; qi < 4; ++qi) {
    int d = tid + qi * 256;
    kgh[b * 1024 + d] = f2b(gelu_f((v[qi] - mean) * inv * g[d] + be[d]));
  }
}

// ---------------- kp + softmax9: one wave per (h,b) ----------------
__global__ __launch_bounds__(64) void k_kp2(const short* __restrict__ kgh, const float* __restrict__ W2,
                                            const float* __restrict__ b2, float* __restrict__ kern)
{
  int h = blockIdx.x, b = blockIdx.y, lane = threadIdx.x;
  float kg[16];
  #pragma unroll
  for (int m = 0; m < 16; ++m) kg[m] = b2f(kgh[b * 1024 + lane + m * 64]);
  float dj[9];
  #pragma unroll
  for (int j = 0; j < 9; ++j) {
    float s = 0;
    #pragma unroll
    for (int m = 0; m < 16; ++m) s += kg[m] * W2[(size_t)(lane + m * 64) * 144 + h * 9 + j];
    #pragma unroll
    for (int off = 32; off; off >>= 1) s += __shfl_xor(s, off);
    dj[j] = s + b2[h * 9 + j];
  }
  if (lane == 0) {
    float m = dj[0];
    #pragma unroll
    for (int j = 1; j < 9; ++j) m = fmaxf(m, dj[j]);
    float e[9], s = 0;
    #pragma unroll
    for (int j = 0; j < 9; ++j) { e[j] = __expf(dj[j] - m); s += e[j]; }
    float inv = 1.0f / s;
    #pragma unroll
    for (int j = 0; j < 9; ++j) kern[(b * 16 + h) * 9 + j] = e[j] * inv;
  }
}

__global__ void k_fail(float* out){ out[threadIdx.x] = 1.0e9f; }

extern "C" void kernel_launch(void* const* d_in, const int* in_sizes, int n_in,
                              void* d_out, int out_size, void* d_ws, size_t ws_size,
                              hipStream_t stream) {
  (void)in_sizes; (void)n_in; (void)out_size;
  const float* x       = (const float*)d_in[0];
  const float* hist    = (const float*)d_in[1];
  const float* Wq      = (const float*)d_in[2];
  const float* Wk      = (const float*)d_in[3];
  const float* Wv      = (const float*)d_in[4];
  const float* hist_W  = (const float*)d_in[5];
  const float* hist_b  = (const float*)d_in[6];
  const float* hln_g   = (const float*)d_in[7];
  const float* hln_b   = (const float*)d_in[8];
  const float* ctx_W1  = (const float*)d_in[9];
  const float* ctx_b1  = (const float*)d_in[10];
  const float* ctx_W2  = (const float*)d_in[11];
  const float* ctx_b2  = (const float*)d_in[12];
  const float* kg_W1   = (const float*)d_in[13];
  const float* kg_b1   = (const float*)d_in[14];
  const float* kln_g   = (const float*)d_in[15];
  const float* kln_b   = (const float*)d_in[16];
  const float* kg_W2   = (const float*)d_in[17];
  const float* kg_b2   = (const float*)d_in[18];
  const float* proj_W  = (const float*)d_in[19];
  const float* proj_b  = (const float*)d_in[20];
  float* outp = (float*)d_out;

  char* wsb = (char*)d_ws;
  size_t off = 0;
  auto nxt = [&](size_t bytes) { void* p = wsb + off; off += (bytes + 255) & ~(size_t)255; return p; };

  short* xb     = (short*)nxt((size_t)4096*1024*2);
  short* wqkvt  = (short*)nxt((size_t)3*1024*1024*2);
  short* qb     = (short*)nxt((size_t)64*1026*64*2);   // padded
  short* kb     = (short*)nxt((size_t)64*1026*64*2);   // padded
  short* vtb    = (short*)nxt((size_t)64*64*1024*2);
  short* Ob     = (short*)nxt((size_t)4096*1024*2);
  short* histb  = (short*)nxt((size_t)1024*1024*2);
  short* whtb   = (short*)nxt((size_t)2048*1024*2);
  float* ehpreP = (float*)nxt((size_t)2*1024*2048*4);  // 2 split-K partials
  short* ehb    = (short*)nxt((size_t)1024*2048*2);
  short* wc1tb  = (short*)nxt((size_t)512*2048*2);
  float* ctxP   = (float*)nxt((size_t)4*1024*512*4);   // 4 split-K partials
  float* tbuf   = (float*)nxt((size_t)1024*512*4);
  float* logit  = (float*)nxt((size_t)1024*4);
  float* ccb    = (float*)nxt((size_t)4*2048*4);
  float* kgpart = (float*)nxt((size_t)128*1024*4);
  short* kghb   = (short*)nxt((size_t)4*1024*2);
  float* kernb  = (float*)nxt((size_t)64*9*4);
  short* wptb   = (short*)nxt((size_t)1024*1024*2);

  if (ws_size < off) { k_fail<<<1, 64, 0, stream>>>(outp); return; }

  // casts + pad zeroing + weight transposes
  k_cast_all<<<2568, 256, 0, stream>>>(x, hist, xb, histb, qb, kb);
  k_tcast_all<<<7168, 256, 0, stream>>>(Wq, Wk, Wv, proj_W, hist_W, ctx_W1, wqkvt, wptb, whtb, wc1tb);

  // context path (split-K on the two skinny GEMMs)
  k_gemm_f32out<<<dim3(16, 8, 2), 256, 0, stream>>>(histb, whtb, ehpreP, nullptr, 2048, 1024, 512, 2);
  k_ln_gelu2048<<<1024, 256, 0, stream>>>(ehpreP, hist_b, hln_g, hln_b, ehb);
  k_gemm_f32out<<<dim3(4, 8, 4), 256, 0, stream>>>(ehb, wc1tb, ctxP, nullptr, 512, 2048, 512, 2);
  k_red_gelu<<<512, 256, 0, stream>>>(ctxP, ctx_b1, tbuf);
  k_aw_logit<<<256, 256, 0, stream>>>(tbuf, ctx_W2, ctx_b2, logit);
  k_softmax_cc<<<dim3(8, 4), 256, 0, stream>>>(logit, ehb, ccb);
  k_kg1p<<<dim3(4, 32), 256, 0, stream>>>(ccb, kg_W1, kgpart);
  k_kg_mid<<<4, 256, 0, stream>>>(kgpart, kg_b1, kln_g, kln_b, kghb);
  k_kp2<<<dim3(16, 4), 64, 0, stream>>>(kghb, kg_W2, kg_b2, kernb);

  // attention path
  k_gemm_qkv<<<dim3(24, 32), 256, 0, stream>>>(xb, wqkvt, qb, kb, vtb);
  k_attn<<<dim3(8, 64), 512, 0, stream>>>(qb, kb, vtb, kernb, Ob);
  k_gemm_f32out<<<dim3(8, 32, 1), 256, 0, stream>>>(Ob, wptb, outp, proj_b, 1024, 1024, 1024, 0);
}